// Round 6
// baseline (870.003 us; speedup 1.0000x reference)
//
#include <hip/hip_runtime.h>
#include <hip/hip_fp16.h>
#include <math.h>

#define NN 262144        // total nodes
#define NE 2097152       // total edges
#define RR 2191          // ref nodes
#define ER (RR*16)       // ref edges = 35056
#define NB 16            // batch graphs
#define BRR (NB*RR)      // 35056
#define OUT_RES (BRR*3)  // 105168

typedef __attribute__((ext_vector_type(8))) _Float16 half8;
typedef __attribute__((ext_vector_type(4))) float f32x4;

// ---------------- degree histogram ----------------
__global__ void k_hist(const int* __restrict__ row, int* __restrict__ deg, int nE){
  int i = blockIdx.x*blockDim.x + threadIdx.x;
  int st = gridDim.x*blockDim.x;
  for (; i < nE; i += st) atomicAdd(&deg[row[i]], 1);
}

// ---------------- exclusive scan (3-phase for N); also emits dinv ----------------
__global__ void k_scan1(const int* __restrict__ deg, int* __restrict__ rowptr,
                        int* __restrict__ partials, float* __restrict__ dinv){
  __shared__ int s[256];
  int t = threadIdx.x; int i = blockIdx.x*256 + t;
  int v = deg[i]; s[t] = v; __syncthreads();
  dinv[i] = v > 0 ? 1.0f/sqrtf((float)v) : 0.0f;
  for (int off = 1; off < 256; off <<= 1){
    int x = (t >= off) ? s[t-off] : 0; __syncthreads();
    s[t] += x; __syncthreads();
  }
  rowptr[i] = s[t] - v;
  if (t == 255) partials[blockIdx.x] = s[255];
}

__global__ void k_scan2(int* __restrict__ partials){
  __shared__ int s[1024];
  int t = threadIdx.x; int v = partials[t]; s[t] = v; __syncthreads();
  for (int off = 1; off < 1024; off <<= 1){
    int x = (t >= off) ? s[t-off] : 0; __syncthreads();
    s[t] += x; __syncthreads();
  }
  partials[t] = s[t] - v;
}

__global__ void k_scan3(int* __restrict__ rowptr, const int* __restrict__ partials){
  int t = threadIdx.x; int i = blockIdx.x*256 + t;
  rowptr[i] += partials[blockIdx.x];
  if (i == 0) rowptr[NN] = NE;
}

// single-block scan for the small ref graph; also emits dinvR
__global__ void k_scan_small(const int* __restrict__ deg, int* __restrict__ rowptr,
                             float* __restrict__ dinv, int n){
  __shared__ int s[256];
  int t = threadIdx.x;
  int carry = 0;
  for (int base = 0; base < n; base += 256){
    int idx = base + t;
    int v = (idx < n) ? deg[idx] : 0;
    if (idx < n) dinv[idx] = v > 0 ? 1.0f/sqrtf((float)v) : 0.0f;
    s[t] = v; __syncthreads();
    for (int off = 1; off < 256; off <<= 1){
      int x = (t >= off) ? s[t-off] : 0; __syncthreads();
      s[t] += x; __syncthreads();
    }
    if (idx < n) rowptr[idx] = carry + s[t] - v;
    carry += s[255];
    __syncthreads();
  }
  if (t == 0) rowptr[n] = carry;
}

// ---------------- CSR scatter (col only; weights separable via dinv) ----------
__global__ void k_scatter(const int* __restrict__ row, const int* __restrict__ col,
                          const int* __restrict__ rowptr, int* __restrict__ cursor,
                          int* __restrict__ csr_col, int nE){
  int i = blockIdx.x*blockDim.x + threadIdx.x;
  int st = gridDim.x*blockDim.x;
  for (; i < nE; i += st){
    int r = row[i];
    int pos = rowptr[r] + atomicAdd(&cursor[r], 1);
    csr_col[pos] = col[i];
  }
}

// ---------------- prop 3-ch f32: y_i = -dinv_i * sum dinv_c * h_c ----------------
__global__ void k_prop3(const float* __restrict__ h, float* __restrict__ y,
                        const int* __restrict__ rowptr, const int* __restrict__ cols,
                        const float* __restrict__ dinv, int n){
  int i = blockIdx.x*blockDim.x + threadIdx.x;
  if (i >= n) return;
  float di = dinv[i];
  float a0 = 0.f, a1 = 0.f, a2 = 0.f;
  int s = rowptr[i], e = rowptr[i+1];
  int p = s;
  for (; p + 4 <= e; p += 4){
    int c0 = cols[p], c1 = cols[p+1], c2 = cols[p+2], c3 = cols[p+3];
    float w0 = dinv[c0], w1 = dinv[c1], w2 = dinv[c2], w3 = dinv[c3];
    float x00=h[c0*3+0], x01=h[c0*3+1], x02=h[c0*3+2];
    float x10=h[c1*3+0], x11=h[c1*3+1], x12=h[c1*3+2];
    float x20=h[c2*3+0], x21=h[c2*3+1], x22=h[c2*3+2];
    float x30=h[c3*3+0], x31=h[c3*3+1], x32=h[c3*3+2];
    a0 = fmaf(w0,x00, fmaf(w1,x10, fmaf(w2,x20, fmaf(w3,x30, a0))));
    a1 = fmaf(w0,x01, fmaf(w1,x11, fmaf(w2,x21, fmaf(w3,x31, a1))));
    a2 = fmaf(w0,x02, fmaf(w1,x12, fmaf(w2,x22, fmaf(w3,x32, a2))));
  }
  for (; p < e; p++){
    int c = cols[p]; float wv = dinv[c];
    a0 = fmaf(wv, h[c*3+0], a0); a1 = fmaf(wv, h[c*3+1], a1); a2 = fmaf(wv, h[c*3+2], a2);
  }
  y[i*3+0] = -di*a0; y[i*3+1] = -di*a1; y[i*3+2] = -di*a2;
}

// ---------------- f32 64-ch prop (ref stack only) ----------------
__global__ void k_prop64(const float* __restrict__ h, float* __restrict__ y,
                         const int* __restrict__ rowptr, const int* __restrict__ cols,
                         const float* __restrict__ dinv, int n){
  int t = threadIdx.x, lane = t & 63;
  int i = blockIdx.x*4 + (t >> 6);
  if (i >= n) return;
  float di = dinv[i];
  float acc = 0.f;
  int s = rowptr[i], e = rowptr[i+1];
  int p = s;
  for (; p + 4 <= e; p += 4){
    int c0 = cols[p], c1 = cols[p+1], c2 = cols[p+2], c3 = cols[p+3];
    float v0 = h[(size_t)c0*64 + lane], v1 = h[(size_t)c1*64 + lane];
    float v2 = h[(size_t)c2*64 + lane], v3 = h[(size_t)c3*64 + lane];
    acc = fmaf(dinv[c0],v0, fmaf(dinv[c1],v1, fmaf(dinv[c2],v2, fmaf(dinv[c3],v3, acc))));
  }
  for (; p < e; p++) acc = fmaf(dinv[cols[p]], h[(size_t)cols[p]*64 + lane], acc);
  y[(size_t)i*64 + lane] = -di*acc;
}

// ---------------- f16 64-ch prop: 16 lanes/row (4 ch each), unroll 8 ----------
__global__ void __launch_bounds__(256) k_prop64h(
    const uint2* __restrict__ h2, uint2* __restrict__ y2,
    const int* __restrict__ rowptr, const int* __restrict__ cols,
    const float* __restrict__ dinv, int n){
  int t = threadIdx.x;
  int sub = t & 15;                     // 8B chunk within the 128B row
  int row = blockIdx.x*16 + (t >> 4);
  if (row >= n) return;
  int s = rowptr[row], e = rowptr[row+1];
  float di = dinv[row];
  float a0=0.f, a1=0.f, a2=0.f, a3=0.f;
  int p = s;
  for (; p + 8 <= e; p += 8){
    int c[8]; uint2 v[8]; float wv[8];
    #pragma unroll
    for (int j = 0; j < 8; j++) c[j] = cols[p+j];
    #pragma unroll
    for (int j = 0; j < 8; j++) v[j] = h2[(size_t)c[j]*16 + sub];
    #pragma unroll
    for (int j = 0; j < 8; j++) wv[j] = dinv[c[j]];
    #pragma unroll
    for (int j = 0; j < 8; j++){
      float2 fa = __half22float2(*(__half2*)&v[j].x);
      float2 fb = __half22float2(*(__half2*)&v[j].y);
      a0 = fmaf(wv[j], fa.x, a0); a1 = fmaf(wv[j], fa.y, a1);
      a2 = fmaf(wv[j], fb.x, a2); a3 = fmaf(wv[j], fb.y, a3);
    }
  }
  for (; p + 4 <= e; p += 4){
    int c[4]; uint2 v[4]; float wv[4];
    #pragma unroll
    for (int j = 0; j < 4; j++) c[j] = cols[p+j];
    #pragma unroll
    for (int j = 0; j < 4; j++) v[j] = h2[(size_t)c[j]*16 + sub];
    #pragma unroll
    for (int j = 0; j < 4; j++) wv[j] = dinv[c[j]];
    #pragma unroll
    for (int j = 0; j < 4; j++){
      float2 fa = __half22float2(*(__half2*)&v[j].x);
      float2 fb = __half22float2(*(__half2*)&v[j].y);
      a0 = fmaf(wv[j], fa.x, a0); a1 = fmaf(wv[j], fa.y, a1);
      a2 = fmaf(wv[j], fb.x, a2); a3 = fmaf(wv[j], fb.y, a3);
    }
  }
  for (; p < e; p++){
    int c = cols[p];
    float wv = dinv[c];
    uint2 v = h2[(size_t)c*16 + sub];
    float2 fa = __half22float2(*(__half2*)&v.x), fb = __half22float2(*(__half2*)&v.y);
    a0 = fmaf(wv, fa.x, a0); a1 = fmaf(wv, fa.y, a1);
    a2 = fmaf(wv, fb.x, a2); a3 = fmaf(wv, fb.y, a3);
  }
  __half2 lo = __floats2half2_rn(-di*a0, -di*a1), hi = __floats2half2_rn(-di*a2, -di*a3);
  uint2 r; r.x = *(unsigned*)&lo; r.y = *(unsigned*)&hi;
  y2[(size_t)row*16 + sub] = r;
}

// ---------------- Cheb combine, layer-1 (3 input channels) ----------------
__global__ void k_combine3f(const float* __restrict__ x, const float* __restrict__ t1,
                            const float* __restrict__ t2, const float* __restrict__ W,
                            const float* __restrict__ bias, float* __restrict__ out, int n){
  int t = threadIdx.x, lane = t & 63;
  int i = blockIdx.x*4 + (t >> 6);
  if (i >= n) return;
  float acc = bias[lane];
  #pragma unroll
  for (int j = 0; j < 3; j++){
    float x0 = x[i*3+j], x1 = t1[i*3+j];
    float x2 = 2.0f*t2[i*3+j] - x0;
    acc += x0*W[      j*64 + lane]
         + x1*W[192 + j*64 + lane]
         + x2*W[384 + j*64 + lane];
  }
  out[(size_t)i*64 + lane] = tanhf(acc);
}

__global__ void k_combine3h(const float* __restrict__ x, const float* __restrict__ t1,
                            const float* __restrict__ t2, const float* __restrict__ W,
                            const float* __restrict__ bias, __half* __restrict__ out, int n){
  int t = threadIdx.x, lane = t & 63;
  int i = blockIdx.x*4 + (t >> 6);
  if (i >= n) return;
  float acc = bias[lane];
  #pragma unroll
  for (int j = 0; j < 3; j++){
    float x0 = x[i*3+j], x1 = t1[i*3+j];
    float x2 = 2.0f*t2[i*3+j] - x0;
    acc += x0*W[      j*64 + lane]
         + x1*W[192 + j*64 + lane]
         + x2*W[384 + j*64 + lane];
  }
  out[(size_t)i*64 + lane] = __float2half_rn(tanhf(acc));
}

// ---------------- effective weights: {W0 - W2, W1, 2*W2} (f32) ----------------
__global__ void k_weff(const float* __restrict__ W, float* __restrict__ D){
  int i = blockIdx.x*blockDim.x + threadIdx.x;  // 4096 threads
  D[i]        = W[i] - W[8192 + i];
  D[4096 + i] = W[4096 + i];
  D[8192 + i] = 2.0f * W[8192 + i];
}

// ---------------- pack layer-2 weights into MFMA B-fragments (f16) -----------
__global__ void k_wpack(const float* __restrict__ W, _Float16* __restrict__ D){
  int t = blockIdx.x*blockDim.x + threadIdx.x;   // 12288
  int reg = t & 7, lane = (t >> 3) & 63, nt = (t >> 9) & 3, kc = t >> 11;
  int m = kc >> 1;
  int kin = (kc & 1)*32 + ((lane >> 4) & 3)*8 + reg;
  int n = nt*16 + (lane & 15);
  float eff;
  if      (m == 0) eff = W[kin*64 + n] - W[8192 + kin*64 + n];
  else if (m == 1) eff = W[4096 + kin*64 + n];
  else             eff = 2.0f * W[8192 + kin*64 + n];
  D[t] = (_Float16)eff;
}

// ---------------- MFMA Cheb combine (layer 2) ----------------
__global__ void __launch_bounds__(256) k_combine64m(
    const __half* A, const __half* B, const __half* C,
    const _Float16* __restrict__ wfrag, const float* __restrict__ bias,
    __half* out, int ntiles, int wavestride){
  int t = threadIdx.x;
  int lane = t & 63;
  int wv = blockIdx.x*4 + (t >> 6);
  half8 bf[24];
  #pragma unroll
  for (int i = 0; i < 24; i++)
    bf[i] = *(const half8*)(wfrag + ((size_t)(i*64 + lane))*8);
  int col = lane & 15, grp = (lane >> 4) & 3;
  float b0 = bias[col], b1 = bias[16+col], b2 = bias[32+col], b3 = bias[48+col];
  for (int tile = wv; tile < ntiles; tile += wavestride){
    size_t rb = (size_t)tile*16;
    f32x4 acc0 = {b0,b0,b0,b0}, acc1 = {b1,b1,b1,b1};
    f32x4 acc2 = {b2,b2,b2,b2}, acc3 = {b3,b3,b3,b3};
    #pragma unroll
    for (int kc = 0; kc < 6; kc++){
      const __half* s = (kc < 2) ? A : (kc < 4) ? B : C;
      half8 a = *(const half8*)(s + (rb + col)*64 + (kc & 1)*32 + grp*8);
      acc0 = __builtin_amdgcn_mfma_f32_16x16x32_f16(a, bf[kc*4+0], acc0, 0,0,0);
      acc1 = __builtin_amdgcn_mfma_f32_16x16x32_f16(a, bf[kc*4+1], acc1, 0,0,0);
      acc2 = __builtin_amdgcn_mfma_f32_16x16x32_f16(a, bf[kc*4+2], acc2, 0,0,0);
      acc3 = __builtin_amdgcn_mfma_f32_16x16x32_f16(a, bf[kc*4+3], acc3, 0,0,0);
    }
    __half* o = out + (rb + grp*4)*64;
    #pragma unroll
    for (int r = 0; r < 4; r++){
      o[(size_t)r*64 +      col] = __float2half_rn(tanhf(acc0[r]));
      o[(size_t)r*64 + 16 + col] = __float2half_rn(tanhf(acc1[r]));
      o[(size_t)r*64 + 32 + col] = __float2half_rn(tanhf(acc2[r]));
      o[(size_t)r*64 + 48 + col] = __float2half_rn(tanhf(acc3[r]));
    }
  }
}

// ---------------- segment sums of 3 f16 buffers ----------------
__global__ void k_pool3(const __half2* __restrict__ hA, const __half2* __restrict__ hB,
                        const __half2* __restrict__ hC, float* __restrict__ pA,
                        float* __restrict__ pB, float* __restrict__ pC){
  const __half2* src = (blockIdx.y == 0) ? hA : (blockIdx.y == 1) ? hB : hC;
  float* dst         = (blockIdx.y == 0) ? pA : (blockIdx.y == 1) ? pB : pC;
  int blk = blockIdx.x;                 // 512: seg*16 + chunk
  int chunk = blk & 15, seg = blk >> 4;
  int t = threadIdx.x, ch2 = t & 31, rsub = t >> 5;
  int base = seg*8192 + chunk*512;
  float ax = 0.f, ay = 0.f;
  for (int j = 0; j < 64; j++){
    int row = base + rsub + j*8;
    float2 v = __half22float2(src[(size_t)row*32 + ch2]);
    ax += v.x; ay += v.y;
  }
  __shared__ float sx[256], sy[256];
  sx[t] = ax; sy[t] = ay; __syncthreads();
  if (t < 32){
    float tx = 0.f, ty = 0.f;
    #pragma unroll
    for (int j = 0; j < 8; j++){ tx += sx[ch2 + j*32]; ty += sy[ch2 + j*32]; }
    int b = seg >> 1, half_ = seg & 1;
    atomicAdd(&dst[half_*1024 + b*64 + ch2*2],     tx);
    atomicAdd(&dst[half_*1024 + b*64 + ch2*2 + 1], ty);
  }
}

// ---------------- pooled layer-3 combine ----------------
__global__ void k_combine_pooled(const float* __restrict__ pA, const float* __restrict__ pB,
                                 const float* __restrict__ pC, const float* __restrict__ weff,
                                 const float* __restrict__ bias, float* __restrict__ xbbsc,
                                 float* __restrict__ dout){
  int i = blockIdx.x*blockDim.x + threadIdx.x;   // 2048
  int pr = i >> 6, c = i & 63;
  const float* a = pA + pr*64;
  const float* b = pB + pr*64;
  const float* cc = pC + pr*64;
  float v = 0.f;
  for (int k = 0; k < 64; k++){
    v = fmaf(a[k],  weff[        k*64 + c], v);
    v = fmaf(b[k],  weff[4096 +  k*64 + c], v);
    v = fmaf(cc[k], weff[8192 +  k*64 + c], v);
  }
  v = v*(1.0f/8192.0f) + bias[c];
  xbbsc[i] = v;
  dout[OUT_RES + i] = v;
}

// ---------------- Cheb combine 64-ch, f32 (ref stack) ----------------
__global__ void __launch_bounds__(256) k_combine64f(
    const float* __restrict__ A, const float* __restrict__ Bm, const float* __restrict__ C,
    const float* __restrict__ Weff, const float* __restrict__ bias,
    float* __restrict__ out, int n){
  int t = threadIdx.x;
  int lane = t & 63;
  int wid  = __builtin_amdgcn_readfirstlane(t >> 6);
  int half_ = wid & 1;
  int row  = blockIdx.x*128 + (wid >> 1)*64 + lane;
  bool active = (row < n);
  float acc[32];
  #pragma unroll
  for (int c = 0; c < 32; c++) acc[c] = bias[half_*32 + c];
  if (active){
    #pragma unroll 1
    for (int m = 0; m < 3; m++){
      const float* src = (m == 0 ? A : (m == 1 ? Bm : C)) + (size_t)row*64;
      const float* Wm  = Weff + m*4096 + half_*32;
      #pragma unroll 1
      for (int k4 = 0; k4 < 16; k4++){
        float4 a4 = *(const float4*)(src + k4*4);
        const float* wk = Wm + k4*256;
        #pragma unroll
        for (int kk = 0; kk < 4; kk++){
          float a = (kk == 0) ? a4.x : (kk == 1) ? a4.y : (kk == 2) ? a4.z : a4.w;
          #pragma unroll
          for (int c = 0; c < 32; c++)
            acc[c] = fmaf(a, wk[kk*64 + c], acc[c]);
        }
      }
    }
  }
  __syncthreads();
  if (active){
    float* o = out + (size_t)row*64 + half_*32;
    #pragma unroll
    for (int c = 0; c < 32; c++) o[c] = tanhf(acc[c]);
  }
}

// ---------------- fused row-local matmul chain (ref side): 3 matmuls ----------
__global__ void k_refchain(const float* __restrict__ refA, const float* __restrict__ mlp_w,
                           const float* __restrict__ mlp2_w, const float* __restrict__ rep0_w,
                           float* __restrict__ rt3a, int n){
  int t = threadIdx.x, lane = t & 63;
  int i = blockIdx.x*4 + (t >> 6);
  if (i >= n) return;
  float v = refA[i*64 + lane];
  float a = 0.f;
  #pragma unroll
  for (int k = 0; k < 64; k++) a += __shfl(v, k, 64) * mlp_w[k*64 + lane];
  float b = 0.f;
  #pragma unroll
  for (int k = 0; k < 64; k++) b += __shfl(a, k, 64) * mlp2_w[k*64 + lane];
  float c = 0.f;
  #pragma unroll
  for (int k = 0; k < 64; k++) c += __shfl(b, k, 64) * rep0_w[k*64 + lane];
  rt3a[i*64 + lane] = c;
}

// ---------------- fused row-local chain (batch side): bb/sc terms -------------
__global__ void k_bbchain(const float* __restrict__ xbbsc,
                          const float* __restrict__ mlp_w,  const float* __restrict__ mlp_b,
                          const float* __restrict__ mlp2_w, const float* __restrict__ mlp2_b,
                          const float* __restrict__ rep0_w, const float* __restrict__ rep0_b,
                          float* __restrict__ bt3a){
  int t = threadIdx.x, lane = t & 63;
  int i = blockIdx.x*4 + (t >> 6);
  if (i >= NB) return;
  float vbb = xbbsc[i*64 + lane];
  float vsc = xbbsc[1024 + i*64 + lane];
  float a = mlp_b[lane];
  #pragma unroll
  for (int k = 0; k < 64; k++) a += __shfl(vbb, k, 64) * mlp_w[4096 + k*64 + lane];
  float b = mlp2_b[lane];
  #pragma unroll
  for (int k = 0; k < 64; k++) b += __shfl(a, k, 64) * mlp2_w[k*64 + lane];
  #pragma unroll
  for (int k = 0; k < 64; k++) b += __shfl(vsc, k, 64) * mlp2_w[4096 + k*64 + lane];
  float c = rep0_b[lane];
  #pragma unroll
  for (int k = 0; k < 64; k++) c += __shfl(b, k, 64) * rep0_w[k*64 + lane];
  bt3a[i*64 + lane] = c;
}

// ---------------- final: relu(rt3[r]+bt3[b]) -> rep1+relu -> rep2+relu ----------------
__global__ void k_final(const float* __restrict__ rt3, const float* __restrict__ bt3,
                        const float* __restrict__ W1, const float* __restrict__ b1,
                        const float* __restrict__ W2, const float* __restrict__ b2,
                        float* __restrict__ dout){
  int t = threadIdx.x, lane = t & 63;
  int g = blockIdx.x*4 + (t >> 6);
  if (g >= BRR) return;
  int b = g / RR, r = g - b*RR;
  float m = rt3[r*64 + lane] + bt3[b*64 + lane];
  m = fmaxf(m, 0.0f);
  float acc = b1[lane];
  #pragma unroll
  for (int k = 0; k < 64; k++) acc += __shfl(m, k, 64) * W1[k*64 + lane];
  float u = fmaxf(acc, 0.0f);
  float p0 = u*W2[lane*3+0], p1 = u*W2[lane*3+1], p2 = u*W2[lane*3+2];
  #pragma unroll
  for (int off = 32; off > 0; off >>= 1){
    p0 += __shfl_xor(p0, off, 64);
    p1 += __shfl_xor(p1, off, 64);
    p2 += __shfl_xor(p2, off, 64);
  }
  if (lane == 0){
    dout[g*3+0] = fmaxf(p0 + b2[0], 0.0f);
    dout[g*3+1] = fmaxf(p1 + b2[1], 0.0f);
    dout[g*3+2] = fmaxf(p2 + b2[2], 0.0f);
  }
}

extern "C" void kernel_launch(void* const* d_in, const int* in_sizes, int n_in,
                              void* d_out, int out_size, void* d_ws, size_t ws_size,
                              hipStream_t stream){
  const float* x     = (const float*)d_in[0];
  const int*   eidx  = (const int*)d_in[1];   // [2,E] flat: rows then cols
  const float* x_ref = (const float*)d_in[4];
  const int*   eref  = (const int*)d_in[5];   // [2,ER]
  const float* cw0 = (const float*)d_in[6],  *cb0 = (const float*)d_in[7];
  const float* cw1 = (const float*)d_in[8],  *cb1 = (const float*)d_in[9];
  const float* cw2 = (const float*)d_in[10], *cb2 = (const float*)d_in[11];
  const float* rw0 = (const float*)d_in[12], *rb0 = (const float*)d_in[13];
  const float* rw1 = (const float*)d_in[14], *rb1 = (const float*)d_in[15];
  const float* rw2 = (const float*)d_in[16], *rb2 = (const float*)d_in[17];
  const float* mlp_w  = (const float*)d_in[18], *mlp_b  = (const float*)d_in[19];
  const float* mlp2_w = (const float*)d_in[20], *mlp2_b = (const float*)d_in[21];
  const float* rep0_w = (const float*)d_in[22], *rep0_b = (const float*)d_in[23];
  const float* rep1_w = (const float*)d_in[24], *rep1_b = (const float*)d_in[25];
  const float* rep2_w = (const float*)d_in[26], *rep2_b = (const float*)d_in[27];
  float* out = (float*)d_out;

  // ---- workspace allocator (256B aligned) ----
  char* w = (char*)d_ws;
  size_t off = 0;
  auto alloc = [&](size_t bytes)->void*{
    void* p = w + off;
    off = (off + bytes + 255) & ~(size_t)255;
    return p;
  };
  // zero zone (single memset): deg, cursor, degR, cursorR, pooled sums
  int*   deg     = (int*)  alloc(NN*4);
  int*   cursor  = (int*)  alloc(NN*4);
  int*   degR    = (int*)  alloc(RR*4);
  int*   cursorR = (int*)  alloc(RR*4);
  float* poolA   = (float*)alloc(2048*4);
  float* poolB   = (float*)alloc(2048*4);
  float* poolC   = (float*)alloc(2048*4);
  size_t zero_bytes = off;

  int*   rowptr   = (int*)  alloc((NN+1)*4);
  int*   partials = (int*)  alloc(1024*4);
  int*   rowptrR  = (int*)  alloc((RR+1)*4);
  float* dinv     = (float*)alloc(NN*4);
  float* dinvR    = (float*)alloc(RR*4);
  int*   csr_col  = (int*)  alloc((size_t)NE*4);
  int*   csr_colR = (int*)  alloc((size_t)ER*4);
  float* t1_3     = (float*)alloc((size_t)NN*3*4);
  float* t2_3     = (float*)alloc((size_t)NN*3*4);
  float* rt1_3    = (float*)alloc(RR*3*4);
  float* rt2_3    = (float*)alloc(RR*3*4);
  __half* hA      = (__half*)alloc((size_t)NN*64*2);
  __half* hB      = (__half*)alloc((size_t)NN*64*2);
  __half* hC      = (__half*)alloc((size_t)NN*64*2);
  float* refA     = (float*)alloc(RR*64*4);
  float* refB     = (float*)alloc(RR*64*4);
  float* refC     = (float*)alloc(RR*64*4);
  float* xbbsc    = (float*)alloc(2048*4);     // [0..1023]=x_bb, [1024..2047]=x_sc
  float* rt3a     = (float*)alloc(RR*64*4);
  float* bt3a     = (float*)alloc(NB*64*4);
  float* weffC2   = (float*)alloc(12288*4);
  float* weffR1   = (float*)alloc(12288*4);
  float* weffR2   = (float*)alloc(12288*4);
  _Float16* wfragC1 = (_Float16*)alloc(12288*2);
  (void)ws_size; (void)in_sizes; (void)n_in; (void)out_size;

  hipMemsetAsync(d_ws, 0, zero_bytes, stream);

  // ---- effective combine weights ----
  k_weff<<<16, 256, 0, stream>>>(cw2, weffC2);
  k_weff<<<16, 256, 0, stream>>>(rw1, weffR1);
  k_weff<<<16, 256, 0, stream>>>(rw2, weffR2);
  k_wpack<<<48, 256, 0, stream>>>(cw1, wfragC1);

  // ---- CSR build (col-only), main + ref ----
  k_hist<<<2048, 256, 0, stream>>>(eidx, deg, NE);
  k_hist<<<64,   256, 0, stream>>>(eref, degR, ER);
  k_scan1<<<1024, 256, 0, stream>>>(deg, rowptr, partials, dinv);
  k_scan2<<<1, 1024, 0, stream>>>(partials);
  k_scan3<<<1024, 256, 0, stream>>>(rowptr, partials);
  k_scan_small<<<1, 256, 0, stream>>>(degR, rowptrR, dinvR, RR);
  k_scatter<<<2048, 256, 0, stream>>>(eidx, eidx+NE, rowptr, cursor, csr_col, NE);
  k_scatter<<<64,   256, 0, stream>>>(eref, eref+ER, rowptrR, cursorR, csr_colR, ER);

  // ---- main stack layer 1 (3-ch input, f32 math, f16 out) ----
  k_prop3<<<1024, 256, 0, stream>>>(x, t1_3, rowptr, csr_col, dinv, NN);
  k_prop3<<<1024, 256, 0, stream>>>(t1_3, t2_3, rowptr, csr_col, dinv, NN);
  k_combine3h<<<NN/4, 256, 0, stream>>>(x, t1_3, t2_3, cw0, cb0, hA, NN);
  // ---- layer 2 (f16 features, MFMA combine) ----
  k_prop64h<<<NN/16, 256, 0, stream>>>((const uint2*)hA, (uint2*)hB, rowptr, csr_col, dinv, NN);
  k_prop64h<<<NN/16, 256, 0, stream>>>((const uint2*)hB, (uint2*)hC, rowptr, csr_col, dinv, NN);
  k_combine64m<<<1024, 256, 0, stream>>>(hA, hB, hC, wfragC1, cb1, hA, NN/16, 4096);
  // ---- layer 3: props, then pooled (linear) combine ----
  k_prop64h<<<NN/16, 256, 0, stream>>>((const uint2*)hA, (uint2*)hB, rowptr, csr_col, dinv, NN);
  k_prop64h<<<NN/16, 256, 0, stream>>>((const uint2*)hB, (uint2*)hC, rowptr, csr_col, dinv, NN);
  k_pool3<<<dim3(512,3), 256, 0, stream>>>((const __half2*)hA, (const __half2*)hB,
                                           (const __half2*)hC, poolA, poolB, poolC);
  k_combine_pooled<<<8, 256, 0, stream>>>(poolA, poolB, poolC, weffC2, cb2, xbbsc, out);

  // ---- reference stack (f32; tanh after every layer incl. last — source bug) ----
  k_prop3<<<9, 256, 0, stream>>>(x_ref, rt1_3, rowptrR, csr_colR, dinvR, RR);
  k_prop3<<<9, 256, 0, stream>>>(rt1_3, rt2_3, rowptrR, csr_colR, dinvR, RR);
  k_combine3f<<<548, 256, 0, stream>>>(x_ref, rt1_3, rt2_3, rw0, rb0, refA, RR);
  k_prop64<<<548, 256, 0, stream>>>(refA, refB, rowptrR, csr_colR, dinvR, RR);
  k_prop64<<<548, 256, 0, stream>>>(refB, refC, rowptrR, csr_colR, dinvR, RR);
  k_combine64f<<<(RR+127)/128, 256, 0, stream>>>(refA, refB, refC, weffR1, rb1, refA, RR);
  k_prop64<<<548, 256, 0, stream>>>(refA, refB, rowptrR, csr_colR, dinvR, RR);
  k_prop64<<<548, 256, 0, stream>>>(refB, refC, rowptrR, csr_colR, dinvR, RR);
  k_combine64f<<<(RR+127)/128, 256, 0, stream>>>(refA, refB, refC, weffR2, rb2, refA, RR);

  // ---- collapsed MLP head (fused row-local chains) ----
  k_refchain<<<548, 256, 0, stream>>>(refA, mlp_w, mlp2_w, rep0_w, rt3a, RR);
  k_bbchain<<<4, 256, 0, stream>>>(xbbsc, mlp_w, mlp_b, mlp2_w, mlp2_b, rep0_w, rep0_b, bt3a);

  k_final<<<(BRR+3)/4, 256, 0, stream>>>(rt3a, bt3a, rep1_w, rep1_b, rep2_w, rep2_b, out);
}

// Round 7
// 839.944 us; speedup vs baseline: 1.0358x; 1.0358x over previous
//
#include <hip/hip_runtime.h>
#include <hip/hip_fp16.h>
#include <math.h>

#define NN 262144        // total nodes
#define NE 2097152       // total edges
#define RR 2191          // ref nodes
#define ER (RR*16)       // ref edges = 35056
#define NB 16            // batch graphs
#define BRR (NB*RR)      // 35056
#define OUT_RES (BRR*3)  // 105168
#define NBKT 4096        // main-graph buckets (64 rows each)

typedef __attribute__((ext_vector_type(8))) _Float16 half8;
typedef __attribute__((ext_vector_type(4))) float f32x4;

// ---------------- degree histogram ----------------
__global__ void k_hist(const int* __restrict__ row, int* __restrict__ deg, int nE){
  int i = blockIdx.x*blockDim.x + threadIdx.x;
  int st = gridDim.x*blockDim.x;
  for (; i < nE; i += st) atomicAdd(&deg[row[i]], 1);
}

// ---------------- exclusive scan (3-phase for N); also emits dinv ----------------
__global__ void k_scan1(const int* __restrict__ deg, int* __restrict__ rowptr,
                        int* __restrict__ partials, float* __restrict__ dinv){
  __shared__ int s[256];
  int t = threadIdx.x; int i = blockIdx.x*256 + t;
  int v = deg[i]; s[t] = v; __syncthreads();
  dinv[i] = v > 0 ? 1.0f/sqrtf((float)v) : 0.0f;
  for (int off = 1; off < 256; off <<= 1){
    int x = (t >= off) ? s[t-off] : 0; __syncthreads();
    s[t] += x; __syncthreads();
  }
  rowptr[i] = s[t] - v;
  if (t == 255) partials[blockIdx.x] = s[255];
}

__global__ void k_scan2(int* __restrict__ partials){
  __shared__ int s[1024];
  int t = threadIdx.x; int v = partials[t]; s[t] = v; __syncthreads();
  for (int off = 1; off < 1024; off <<= 1){
    int x = (t >= off) ? s[t-off] : 0; __syncthreads();
    s[t] += x; __syncthreads();
  }
  partials[t] = s[t] - v;
}

__global__ void k_scan3(int* __restrict__ rowptr, const int* __restrict__ partials){
  int t = threadIdx.x; int i = blockIdx.x*256 + t;
  rowptr[i] += partials[blockIdx.x];
  if (i == 0) rowptr[NN] = NE;
}

// single-block scan for the small ref graph; also emits dinvR
__global__ void k_scan_small(const int* __restrict__ deg, int* __restrict__ rowptr,
                             float* __restrict__ dinv, int n){
  __shared__ int s[256];
  int t = threadIdx.x;
  int carry = 0;
  for (int base = 0; base < n; base += 256){
    int idx = base + t;
    int v = (idx < n) ? deg[idx] : 0;
    if (idx < n) dinv[idx] = v > 0 ? 1.0f/sqrtf((float)v) : 0.0f;
    s[t] = v; __syncthreads();
    for (int off = 1; off < 256; off <<= 1){
      int x = (t >= off) ? s[t-off] : 0; __syncthreads();
      s[t] += x; __syncthreads();
    }
    if (idx < n) rowptr[idx] = carry + s[t] - v;
    carry += s[255];
    __syncthreads();
  }
  if (t == 0) rowptr[n] = carry;
}

// ---------------- bucketed scatter, pass A: append {rlocal|col, w} to bucket ----
// bucket b covers rows [b*64, b*64+64); its staging region IS the final CSR
// segment [rowptr[b*64], rowptr[(b+1)*64]) -> appends are temporally dense.
__global__ void k_binA(const int* __restrict__ row, const int* __restrict__ col,
                       const float* __restrict__ dinv, const int* __restrict__ rowptr,
                       int* __restrict__ bcur, int2* __restrict__ staging, int nE){
  int i = blockIdx.x*blockDim.x + threadIdx.x;
  int st = gridDim.x*blockDim.x;
  for (; i < nE; i += st){
    int r = row[i], c = col[i];
    int b = r >> 6;
    int pos = rowptr[b << 6] + atomicAdd(&bcur[b], 1);
    float wv = -dinv[r]*dinv[c];
    staging[pos] = make_int2(((r & 63) << 24) | c, __float_as_int(wv));
  }
}

// ---------------- bucketed scatter, pass B: permute bucket into per-row order ---
// One block per bucket; rowptr + row cursors in LDS; writes span a ~4KB window.
__global__ void __launch_bounds__(256) k_binB(const int2* __restrict__ staging,
                                              const int* __restrict__ rowptr,
                                              int2* __restrict__ cpair){
  __shared__ int rp[65];
  __shared__ int rowcur[64];
  int b = blockIdx.x;
  int t = threadIdx.x;
  if (t < 64){ rowcur[t] = 0; rp[t] = rowptr[(b << 6) + t]; }
  if (t == 64) rp[64] = rowptr[(b << 6) + 64];
  __syncthreads();
  int base = rp[0];
  int n_b = rp[64] - base;
  for (int i = t; i < n_b; i += 256){
    int2 pr = staging[base + i];
    int rl = (pr.x >> 24) & 63;
    int c  = pr.x & 0xFFFFFF;
    int idx = atomicAdd(&rowcur[rl], 1);
    cpair[rp[rl] + idx] = make_int2(c, pr.y);
  }
}

// ---------------- simple scatter for the tiny ref graph (packed pairs) ---------
__global__ void k_scatter_ref(const int* __restrict__ row, const int* __restrict__ col,
                              const float* __restrict__ dinv, const int* __restrict__ rowptr,
                              int* __restrict__ cursor, int2* __restrict__ pair, int nE){
  int i = blockIdx.x*blockDim.x + threadIdx.x;
  int st = gridDim.x*blockDim.x;
  for (; i < nE; i += st){
    int r = row[i], c = col[i];
    int pos = rowptr[r] + atomicAdd(&cursor[r], 1);
    pair[pos] = make_int2(c, __float_as_int(-dinv[r]*dinv[c]));
  }
}

// ---------------- prop 3-ch f32 (packed pairs) ----------------
__global__ void k_prop3(const float* __restrict__ h, float* __restrict__ y,
                        const int* __restrict__ rowptr, const int2* __restrict__ pair, int n){
  int i = blockIdx.x*blockDim.x + threadIdx.x;
  if (i >= n) return;
  float a0 = 0.f, a1 = 0.f, a2 = 0.f;
  int s = rowptr[i], e = rowptr[i+1];
  int p = s;
  for (; p + 4 <= e; p += 4){
    int2 q0 = pair[p], q1 = pair[p+1], q2 = pair[p+2], q3 = pair[p+3];
    float w0 = __int_as_float(q0.y), w1 = __int_as_float(q1.y);
    float w2 = __int_as_float(q2.y), w3 = __int_as_float(q3.y);
    float x00=h[q0.x*3+0], x01=h[q0.x*3+1], x02=h[q0.x*3+2];
    float x10=h[q1.x*3+0], x11=h[q1.x*3+1], x12=h[q1.x*3+2];
    float x20=h[q2.x*3+0], x21=h[q2.x*3+1], x22=h[q2.x*3+2];
    float x30=h[q3.x*3+0], x31=h[q3.x*3+1], x32=h[q3.x*3+2];
    a0 = fmaf(w0,x00, fmaf(w1,x10, fmaf(w2,x20, fmaf(w3,x30, a0))));
    a1 = fmaf(w0,x01, fmaf(w1,x11, fmaf(w2,x21, fmaf(w3,x31, a1))));
    a2 = fmaf(w0,x02, fmaf(w1,x12, fmaf(w2,x22, fmaf(w3,x32, a2))));
  }
  for (; p < e; p++){
    int2 q = pair[p]; float wv = __int_as_float(q.y);
    a0 = fmaf(wv, h[q.x*3+0], a0); a1 = fmaf(wv, h[q.x*3+1], a1); a2 = fmaf(wv, h[q.x*3+2], a2);
  }
  y[i*3+0] = a0; y[i*3+1] = a1; y[i*3+2] = a2;
}

// ---------------- f32 64-ch prop (ref stack only, packed pairs) ----------------
__global__ void k_prop64(const float* __restrict__ h, float* __restrict__ y,
                         const int* __restrict__ rowptr, const int2* __restrict__ pair, int n){
  int t = threadIdx.x, lane = t & 63;
  int i = blockIdx.x*4 + (t >> 6);
  if (i >= n) return;
  float acc = 0.f;
  int s = rowptr[i], e = rowptr[i+1];
  int p = s;
  for (; p + 4 <= e; p += 4){
    int2 q0 = pair[p], q1 = pair[p+1], q2 = pair[p+2], q3 = pair[p+3];
    float v0 = h[(size_t)q0.x*64 + lane], v1 = h[(size_t)q1.x*64 + lane];
    float v2 = h[(size_t)q2.x*64 + lane], v3 = h[(size_t)q3.x*64 + lane];
    acc = fmaf(__int_as_float(q0.y),v0, fmaf(__int_as_float(q1.y),v1,
          fmaf(__int_as_float(q2.y),v2, fmaf(__int_as_float(q3.y),v3, acc))));
  }
  for (; p < e; p++){
    int2 q = pair[p];
    acc = fmaf(__int_as_float(q.y), h[(size_t)q.x*64 + lane], acc);
  }
  y[(size_t)i*64 + lane] = acc;
}

// ---------------- f16 64-ch prop: 16 lanes/row, packed pairs, unroll 8/4 -------
__global__ void __launch_bounds__(256) k_prop64h(
    const uint2* __restrict__ h2, uint2* __restrict__ y2,
    const int* __restrict__ rowptr, const int2* __restrict__ pair, int n){
  int t = threadIdx.x;
  int sub = t & 15;                     // 8B chunk within the 128B row
  int row = blockIdx.x*16 + (t >> 4);
  if (row >= n) return;
  int s = rowptr[row], e = rowptr[row+1];
  float a0=0.f, a1=0.f, a2=0.f, a3=0.f;
  int p = s;
  for (; p + 8 <= e; p += 8){
    int2 q[8]; uint2 v[8];
    #pragma unroll
    for (int j = 0; j < 8; j++) q[j] = pair[p+j];
    #pragma unroll
    for (int j = 0; j < 8; j++) v[j] = h2[(size_t)q[j].x*16 + sub];
    #pragma unroll
    for (int j = 0; j < 8; j++){
      float wv = __int_as_float(q[j].y);
      float2 fa = __half22float2(*(__half2*)&v[j].x);
      float2 fb = __half22float2(*(__half2*)&v[j].y);
      a0 = fmaf(wv, fa.x, a0); a1 = fmaf(wv, fa.y, a1);
      a2 = fmaf(wv, fb.x, a2); a3 = fmaf(wv, fb.y, a3);
    }
  }
  for (; p + 4 <= e; p += 4){
    int2 q[4]; uint2 v[4];
    #pragma unroll
    for (int j = 0; j < 4; j++) q[j] = pair[p+j];
    #pragma unroll
    for (int j = 0; j < 4; j++) v[j] = h2[(size_t)q[j].x*16 + sub];
    #pragma unroll
    for (int j = 0; j < 4; j++){
      float wv = __int_as_float(q[j].y);
      float2 fa = __half22float2(*(__half2*)&v[j].x);
      float2 fb = __half22float2(*(__half2*)&v[j].y);
      a0 = fmaf(wv, fa.x, a0); a1 = fmaf(wv, fa.y, a1);
      a2 = fmaf(wv, fb.x, a2); a3 = fmaf(wv, fb.y, a3);
    }
  }
  for (; p < e; p++){
    int2 q = pair[p];
    float wv = __int_as_float(q.y);
    uint2 v = h2[(size_t)q.x*16 + sub];
    float2 fa = __half22float2(*(__half2*)&v.x), fb = __half22float2(*(__half2*)&v.y);
    a0 = fmaf(wv, fa.x, a0); a1 = fmaf(wv, fa.y, a1);
    a2 = fmaf(wv, fb.x, a2); a3 = fmaf(wv, fb.y, a3);
  }
  __half2 lo = __floats2half2_rn(a0, a1), hi = __floats2half2_rn(a2, a3);
  uint2 r; r.x = *(unsigned*)&lo; r.y = *(unsigned*)&hi;
  y2[(size_t)row*16 + sub] = r;
}

// ---------------- Cheb combine, layer-1 (3 input channels) ----------------
__global__ void k_combine3f(const float* __restrict__ x, const float* __restrict__ t1,
                            const float* __restrict__ t2, const float* __restrict__ W,
                            const float* __restrict__ bias, float* __restrict__ out, int n){
  int t = threadIdx.x, lane = t & 63;
  int i = blockIdx.x*4 + (t >> 6);
  if (i >= n) return;
  float acc = bias[lane];
  #pragma unroll
  for (int j = 0; j < 3; j++){
    float x0 = x[i*3+j], x1 = t1[i*3+j];
    float x2 = 2.0f*t2[i*3+j] - x0;
    acc += x0*W[      j*64 + lane]
         + x1*W[192 + j*64 + lane]
         + x2*W[384 + j*64 + lane];
  }
  out[(size_t)i*64 + lane] = tanhf(acc);
}

__global__ void k_combine3h(const float* __restrict__ x, const float* __restrict__ t1,
                            const float* __restrict__ t2, const float* __restrict__ W,
                            const float* __restrict__ bias, __half* __restrict__ out, int n){
  int t = threadIdx.x, lane = t & 63;
  int i = blockIdx.x*4 + (t >> 6);
  if (i >= n) return;
  float acc = bias[lane];
  #pragma unroll
  for (int j = 0; j < 3; j++){
    float x0 = x[i*3+j], x1 = t1[i*3+j];
    float x2 = 2.0f*t2[i*3+j] - x0;
    acc += x0*W[      j*64 + lane]
         + x1*W[192 + j*64 + lane]
         + x2*W[384 + j*64 + lane];
  }
  out[(size_t)i*64 + lane] = __float2half_rn(tanhf(acc));
}

// ---------------- effective weights: {W0 - W2, W1, 2*W2} (f32) ----------------
__global__ void k_weff(const float* __restrict__ W, float* __restrict__ D){
  int i = blockIdx.x*blockDim.x + threadIdx.x;  // 4096 threads
  D[i]        = W[i] - W[8192 + i];
  D[4096 + i] = W[4096 + i];
  D[8192 + i] = 2.0f * W[8192 + i];
}

// ---------------- pack layer-2 weights into MFMA B-fragments (f16) -----------
__global__ void k_wpack(const float* __restrict__ W, _Float16* __restrict__ D){
  int t = blockIdx.x*blockDim.x + threadIdx.x;   // 12288
  int reg = t & 7, lane = (t >> 3) & 63, nt = (t >> 9) & 3, kc = t >> 11;
  int m = kc >> 1;
  int kin = (kc & 1)*32 + ((lane >> 4) & 3)*8 + reg;
  int n = nt*16 + (lane & 15);
  float eff;
  if      (m == 0) eff = W[kin*64 + n] - W[8192 + kin*64 + n];
  else if (m == 1) eff = W[4096 + kin*64 + n];
  else             eff = 2.0f * W[8192 + kin*64 + n];
  D[t] = (_Float16)eff;
}

// ---------------- MFMA Cheb combine (layer 2) ----------------
__global__ void __launch_bounds__(256) k_combine64m(
    const __half* A, const __half* B, const __half* C,
    const _Float16* __restrict__ wfrag, const float* __restrict__ bias,
    __half* out, int ntiles, int wavestride){
  int t = threadIdx.x;
  int lane = t & 63;
  int wv = blockIdx.x*4 + (t >> 6);
  half8 bf[24];
  #pragma unroll
  for (int i = 0; i < 24; i++)
    bf[i] = *(const half8*)(wfrag + ((size_t)(i*64 + lane))*8);
  int col = lane & 15, grp = (lane >> 4) & 3;
  float b0 = bias[col], b1 = bias[16+col], b2 = bias[32+col], b3 = bias[48+col];
  for (int tile = wv; tile < ntiles; tile += wavestride){
    size_t rb = (size_t)tile*16;
    f32x4 acc0 = {b0,b0,b0,b0}, acc1 = {b1,b1,b1,b1};
    f32x4 acc2 = {b2,b2,b2,b2}, acc3 = {b3,b3,b3,b3};
    #pragma unroll
    for (int kc = 0; kc < 6; kc++){
      const __half* s = (kc < 2) ? A : (kc < 4) ? B : C;
      half8 a = *(const half8*)(s + (rb + col)*64 + (kc & 1)*32 + grp*8);
      acc0 = __builtin_amdgcn_mfma_f32_16x16x32_f16(a, bf[kc*4+0], acc0, 0,0,0);
      acc1 = __builtin_amdgcn_mfma_f32_16x16x32_f16(a, bf[kc*4+1], acc1, 0,0,0);
      acc2 = __builtin_amdgcn_mfma_f32_16x16x32_f16(a, bf[kc*4+2], acc2, 0,0,0);
      acc3 = __builtin_amdgcn_mfma_f32_16x16x32_f16(a, bf[kc*4+3], acc3, 0,0,0);
    }
    __half* o = out + (rb + grp*4)*64;
    #pragma unroll
    for (int r = 0; r < 4; r++){
      o[(size_t)r*64 +      col] = __float2half_rn(tanhf(acc0[r]));
      o[(size_t)r*64 + 16 + col] = __float2half_rn(tanhf(acc1[r]));
      o[(size_t)r*64 + 32 + col] = __float2half_rn(tanhf(acc2[r]));
      o[(size_t)r*64 + 48 + col] = __float2half_rn(tanhf(acc3[r]));
    }
  }
}

// ---------------- segment sums of 3 f16 buffers ----------------
__global__ void k_pool3(const __half2* __restrict__ hA, const __half2* __restrict__ hB,
                        const __half2* __restrict__ hC, float* __restrict__ pA,
                        float* __restrict__ pB, float* __restrict__ pC){
  const __half2* src = (blockIdx.y == 0) ? hA : (blockIdx.y == 1) ? hB : hC;
  float* dst         = (blockIdx.y == 0) ? pA : (blockIdx.y == 1) ? pB : pC;
  int blk = blockIdx.x;                 // 512: seg*16 + chunk
  int chunk = blk & 15, seg = blk >> 4;
  int t = threadIdx.x, ch2 = t & 31, rsub = t >> 5;
  int base = seg*8192 + chunk*512;
  float ax = 0.f, ay = 0.f;
  for (int j = 0; j < 64; j++){
    int row = base + rsub + j*8;
    float2 v = __half22float2(src[(size_t)row*32 + ch2]);
    ax += v.x; ay += v.y;
  }
  __shared__ float sx[256], sy[256];
  sx[t] = ax; sy[t] = ay; __syncthreads();
  if (t < 32){
    float tx = 0.f, ty = 0.f;
    #pragma unroll
    for (int j = 0; j < 8; j++){ tx += sx[ch2 + j*32]; ty += sy[ch2 + j*32]; }
    int b = seg >> 1, half_ = seg & 1;
    atomicAdd(&dst[half_*1024 + b*64 + ch2*2],     tx);
    atomicAdd(&dst[half_*1024 + b*64 + ch2*2 + 1], ty);
  }
}

// ---------------- pooled layer-3 combine ----------------
__global__ void k_combine_pooled(const float* __restrict__ pA, const float* __restrict__ pB,
                                 const float* __restrict__ pC, const float* __restrict__ weff,
                                 const float* __restrict__ bias, float* __restrict__ xbbsc,
                                 float* __restrict__ dout){
  int i = blockIdx.x*blockDim.x + threadIdx.x;   // 2048
  int pr = i >> 6, c = i & 63;
  const float* a = pA + pr*64;
  const float* b = pB + pr*64;
  const float* cc = pC + pr*64;
  float v = 0.f;
  for (int k = 0; k < 64; k++){
    v = fmaf(a[k],  weff[        k*64 + c], v);
    v = fmaf(b[k],  weff[4096 +  k*64 + c], v);
    v = fmaf(cc[k], weff[8192 +  k*64 + c], v);
  }
  v = v*(1.0f/8192.0f) + bias[c];
  xbbsc[i] = v;
  dout[OUT_RES + i] = v;
}

// ---------------- Cheb combine 64-ch, f32 (ref stack) ----------------
__global__ void __launch_bounds__(256) k_combine64f(
    const float* __restrict__ A, const float* __restrict__ Bm, const float* __restrict__ C,
    const float* __restrict__ Weff, const float* __restrict__ bias,
    float* __restrict__ out, int n){
  int t = threadIdx.x;
  int lane = t & 63;
  int wid  = __builtin_amdgcn_readfirstlane(t >> 6);
  int half_ = wid & 1;
  int row  = blockIdx.x*128 + (wid >> 1)*64 + lane;
  bool active = (row < n);
  float acc[32];
  #pragma unroll
  for (int c = 0; c < 32; c++) acc[c] = bias[half_*32 + c];
  if (active){
    #pragma unroll 1
    for (int m = 0; m < 3; m++){
      const float* src = (m == 0 ? A : (m == 1 ? Bm : C)) + (size_t)row*64;
      const float* Wm  = Weff + m*4096 + half_*32;
      #pragma unroll 1
      for (int k4 = 0; k4 < 16; k4++){
        float4 a4 = *(const float4*)(src + k4*4);
        const float* wk = Wm + k4*256;
        #pragma unroll
        for (int kk = 0; kk < 4; kk++){
          float a = (kk == 0) ? a4.x : (kk == 1) ? a4.y : (kk == 2) ? a4.z : a4.w;
          #pragma unroll
          for (int c = 0; c < 32; c++)
            acc[c] = fmaf(a, wk[kk*64 + c], acc[c]);
        }
      }
    }
  }
  __syncthreads();
  if (active){
    float* o = out + (size_t)row*64 + half_*32;
    #pragma unroll
    for (int c = 0; c < 32; c++) o[c] = tanhf(acc[c]);
  }
}

// ---------------- fused row-local matmul chain (ref side): 3 matmuls ----------
__global__ void k_refchain(const float* __restrict__ refA, const float* __restrict__ mlp_w,
                           const float* __restrict__ mlp2_w, const float* __restrict__ rep0_w,
                           float* __restrict__ rt3a, int n){
  int t = threadIdx.x, lane = t & 63;
  int i = blockIdx.x*4 + (t >> 6);
  if (i >= n) return;
  float v = refA[i*64 + lane];
  float a = 0.f;
  #pragma unroll
  for (int k = 0; k < 64; k++) a += __shfl(v, k, 64) * mlp_w[k*64 + lane];
  float b = 0.f;
  #pragma unroll
  for (int k = 0; k < 64; k++) b += __shfl(a, k, 64) * mlp2_w[k*64 + lane];
  float c = 0.f;
  #pragma unroll
  for (int k = 0; k < 64; k++) c += __shfl(b, k, 64) * rep0_w[k*64 + lane];
  rt3a[i*64 + lane] = c;
}

// ---------------- fused row-local chain (batch side): bb/sc terms -------------
__global__ void k_bbchain(const float* __restrict__ xbbsc,
                          const float* __restrict__ mlp_w,  const float* __restrict__ mlp_b,
                          const float* __restrict__ mlp2_w, const float* __restrict__ mlp2_b,
                          const float* __restrict__ rep0_w, const float* __restrict__ rep0_b,
                          float* __restrict__ bt3a){
  int t = threadIdx.x, lane = t & 63;
  int i = blockIdx.x*4 + (t >> 6);
  if (i >= NB) return;
  float vbb = xbbsc[i*64 + lane];
  float vsc = xbbsc[1024 + i*64 + lane];
  float a = mlp_b[lane];
  #pragma unroll
  for (int k = 0; k < 64; k++) a += __shfl(vbb, k, 64) * mlp_w[4096 + k*64 + lane];
  float b = mlp2_b[lane];
  #pragma unroll
  for (int k = 0; k < 64; k++) b += __shfl(a, k, 64) * mlp2_w[k*64 + lane];
  #pragma unroll
  for (int k = 0; k < 64; k++) b += __shfl(vsc, k, 64) * mlp2_w[4096 + k*64 + lane];
  float c = rep0_b[lane];
  #pragma unroll
  for (int k = 0; k < 64; k++) c += __shfl(b, k, 64) * rep0_w[k*64 + lane];
  bt3a[i*64 + lane] = c;
}

// ---------------- final: relu(rt3[r]+bt3[b]) -> rep1+relu -> rep2+relu ----------------
__global__ void k_final(const float* __restrict__ rt3, const float* __restrict__ bt3,
                        const float* __restrict__ W1, const float* __restrict__ b1,
                        const float* __restrict__ W2, const float* __restrict__ b2,
                        float* __restrict__ dout){
  int t = threadIdx.x, lane = t & 63;
  int g = blockIdx.x*4 + (t >> 6);
  if (g >= BRR) return;
  int b = g / RR, r = g - b*RR;
  float m = rt3[r*64 + lane] + bt3[b*64 + lane];
  m = fmaxf(m, 0.0f);
  float acc = b1[lane];
  #pragma unroll
  for (int k = 0; k < 64; k++) acc += __shfl(m, k, 64) * W1[k*64 + lane];
  float u = fmaxf(acc, 0.0f);
  float p0 = u*W2[lane*3+0], p1 = u*W2[lane*3+1], p2 = u*W2[lane*3+2];
  #pragma unroll
  for (int off = 32; off > 0; off >>= 1){
    p0 += __shfl_xor(p0, off, 64);
    p1 += __shfl_xor(p1, off, 64);
    p2 += __shfl_xor(p2, off, 64);
  }
  if (lane == 0){
    dout[g*3+0] = fmaxf(p0 + b2[0], 0.0f);
    dout[g*3+1] = fmaxf(p1 + b2[1], 0.0f);
    dout[g*3+2] = fmaxf(p2 + b2[2], 0.0f);
  }
}

extern "C" void kernel_launch(void* const* d_in, const int* in_sizes, int n_in,
                              void* d_out, int out_size, void* d_ws, size_t ws_size,
                              hipStream_t stream){
  const float* x     = (const float*)d_in[0];
  const int*   eidx  = (const int*)d_in[1];   // [2,E] flat: rows then cols
  const float* x_ref = (const float*)d_in[4];
  const int*   eref  = (const int*)d_in[5];   // [2,ER]
  const float* cw0 = (const float*)d_in[6],  *cb0 = (const float*)d_in[7];
  const float* cw1 = (const float*)d_in[8],  *cb1 = (const float*)d_in[9];
  const float* cw2 = (const float*)d_in[10], *cb2 = (const float*)d_in[11];
  const float* rw0 = (const float*)d_in[12], *rb0 = (const float*)d_in[13];
  const float* rw1 = (const float*)d_in[14], *rb1 = (const float*)d_in[15];
  const float* rw2 = (const float*)d_in[16], *rb2 = (const float*)d_in[17];
  const float* mlp_w  = (const float*)d_in[18], *mlp_b  = (const float*)d_in[19];
  const float* mlp2_w = (const float*)d_in[20], *mlp2_b = (const float*)d_in[21];
  const float* rep0_w = (const float*)d_in[22], *rep0_b = (const float*)d_in[23];
  const float* rep1_w = (const float*)d_in[24], *rep1_b = (const float*)d_in[25];
  const float* rep2_w = (const float*)d_in[26], *rep2_b = (const float*)d_in[27];
  float* out = (float*)d_out;

  // ---- workspace allocator (256B aligned) ----
  char* w = (char*)d_ws;
  size_t off = 0;
  auto alloc = [&](size_t bytes)->void*{
    void* p = w + off;
    off = (off + bytes + 255) & ~(size_t)255;
    return p;
  };
  // zero zone (single memset): deg, bcur, degR, cursorR, pooled sums
  int*   deg     = (int*)  alloc(NN*4);
  int*   bcur    = (int*)  alloc(NBKT*4);
  int*   degR    = (int*)  alloc(RR*4);
  int*   cursorR = (int*)  alloc(RR*4);
  float* poolA   = (float*)alloc(2048*4);
  float* poolB   = (float*)alloc(2048*4);
  float* poolC   = (float*)alloc(2048*4);
  size_t zero_bytes = off;

  int*   rowptr   = (int*)  alloc((NN+1)*4);
  int*   partials = (int*)  alloc(1024*4);
  int*   rowptrR  = (int*)  alloc((RR+1)*4);
  float* dinv     = (float*)alloc(NN*4);
  float* dinvR    = (float*)alloc(RR*4);
  int2*  staging  = (int2*) alloc((size_t)NE*8);
  int2*  cpair    = (int2*) alloc((size_t)NE*8);
  int2*  cpairR   = (int2*) alloc((size_t)ER*8);
  float* t1_3     = (float*)alloc((size_t)NN*3*4);
  float* t2_3     = (float*)alloc((size_t)NN*3*4);
  float* rt1_3    = (float*)alloc(RR*3*4);
  float* rt2_3    = (float*)alloc(RR*3*4);
  __half* hA      = (__half*)alloc((size_t)NN*64*2);
  __half* hB      = (__half*)alloc((size_t)NN*64*2);
  __half* hC      = (__half*)alloc((size_t)NN*64*2);
  float* refA     = (float*)alloc(RR*64*4);
  float* refB     = (float*)alloc(RR*64*4);
  float* refC     = (float*)alloc(RR*64*4);
  float* xbbsc    = (float*)alloc(2048*4);     // [0..1023]=x_bb, [1024..2047]=x_sc
  float* rt3a     = (float*)alloc(RR*64*4);
  float* bt3a     = (float*)alloc(NB*64*4);
  float* weffC2   = (float*)alloc(12288*4);
  float* weffR1   = (float*)alloc(12288*4);
  float* weffR2   = (float*)alloc(12288*4);
  _Float16* wfragC1 = (_Float16*)alloc(12288*2);
  (void)ws_size; (void)in_sizes; (void)n_in; (void)out_size;

  hipMemsetAsync(d_ws, 0, zero_bytes, stream);

  // ---- effective combine weights ----
  k_weff<<<16, 256, 0, stream>>>(cw2, weffC2);
  k_weff<<<16, 256, 0, stream>>>(rw1, weffR1);
  k_weff<<<16, 256, 0, stream>>>(rw2, weffR2);
  k_wpack<<<48, 256, 0, stream>>>(cw1, wfragC1);

  // ---- CSR build: main = bucketed two-pass; ref = simple ----
  k_hist<<<2048, 256, 0, stream>>>(eidx, deg, NE);
  k_hist<<<64,   256, 0, stream>>>(eref, degR, ER);
  k_scan1<<<1024, 256, 0, stream>>>(deg, rowptr, partials, dinv);
  k_scan2<<<1, 1024, 0, stream>>>(partials);
  k_scan3<<<1024, 256, 0, stream>>>(rowptr, partials);
  k_scan_small<<<1, 256, 0, stream>>>(degR, rowptrR, dinvR, RR);
  k_binA<<<2048, 256, 0, stream>>>(eidx, eidx+NE, dinv, rowptr, bcur, staging, NE);
  k_binB<<<NBKT, 256, 0, stream>>>(staging, rowptr, cpair);
  k_scatter_ref<<<64, 256, 0, stream>>>(eref, eref+ER, dinvR, rowptrR, cursorR, cpairR, ER);

  // ---- main stack layer 1 (3-ch input, f32 math, f16 out) ----
  k_prop3<<<1024, 256, 0, stream>>>(x, t1_3, rowptr, cpair, NN);
  k_prop3<<<1024, 256, 0, stream>>>(t1_3, t2_3, rowptr, cpair, NN);
  k_combine3h<<<NN/4, 256, 0, stream>>>(x, t1_3, t2_3, cw0, cb0, hA, NN);
  // ---- layer 2 (f16 features, MFMA combine) ----
  k_prop64h<<<NN/16, 256, 0, stream>>>((const uint2*)hA, (uint2*)hB, rowptr, cpair, NN);
  k_prop64h<<<NN/16, 256, 0, stream>>>((const uint2*)hB, (uint2*)hC, rowptr, cpair, NN);
  k_combine64m<<<1024, 256, 0, stream>>>(hA, hB, hC, wfragC1, cb1, hA, NN/16, 4096);
  // ---- layer 3: props, then pooled (linear) combine ----
  k_prop64h<<<NN/16, 256, 0, stream>>>((const uint2*)hA, (uint2*)hB, rowptr, cpair, NN);
  k_prop64h<<<NN/16, 256, 0, stream>>>((const uint2*)hB, (uint2*)hC, rowptr, cpair, NN);
  k_pool3<<<dim3(512,3), 256, 0, stream>>>((const __half2*)hA, (const __half2*)hB,
                                           (const __half2*)hC, poolA, poolB, poolC);
  k_combine_pooled<<<8, 256, 0, stream>>>(poolA, poolB, poolC, weffC2, cb2, xbbsc, out);

  // ---- reference stack (f32; tanh after every layer incl. last — source bug) ----
  k_prop3<<<9, 256, 0, stream>>>(x_ref, rt1_3, rowptrR, cpairR, RR);
  k_prop3<<<9, 256, 0, stream>>>(rt1_3, rt2_3, rowptrR, cpairR, RR);
  k_combine3f<<<548, 256, 0, stream>>>(x_ref, rt1_3, rt2_3, rw0, rb0, refA, RR);
  k_prop64<<<548, 256, 0, stream>>>(refA, refB, rowptrR, cpairR, RR);
  k_prop64<<<548, 256, 0, stream>>>(refB, refC, rowptrR, cpairR, RR);
  k_combine64f<<<(RR+127)/128, 256, 0, stream>>>(refA, refB, refC, weffR1, rb1, refA, RR);
  k_prop64<<<548, 256, 0, stream>>>(refA, refB, rowptrR, cpairR, RR);
  k_prop64<<<548, 256, 0, stream>>>(refB, refC, rowptrR, cpairR, RR);
  k_combine64f<<<(RR+127)/128, 256, 0, stream>>>(refA, refB, refC, weffR2, rb2, refA, RR);

  // ---- collapsed MLP head (fused row-local chains) ----
  k_refchain<<<548, 256, 0, stream>>>(refA, mlp_w, mlp2_w, rep0_w, rt3a, RR);
  k_bbchain<<<4, 256, 0, stream>>>(xbbsc, mlp_w, mlp_b, mlp2_w, mlp2_b, rep0_w, rep0_b, bt3a);

  k_final<<<(BRR+3)/4, 256, 0, stream>>>(rt3a, bt3a, rep1_w, rep1_b, rep2_w, rep2_b, out);
}

// Round 8
// 769.936 us; speedup vs baseline: 1.1300x; 1.0909x over previous
//
#include <hip/hip_runtime.h>
#include <hip/hip_fp16.h>
#include <math.h>

#define NN 262144        // total nodes
#define NE 2097152       // total edges
#define RR 2191          // ref nodes
#define ER (RR*16)       // ref edges = 35056
#define NB 16            // batch graphs
#define BRR (NB*RR)      // 35056
#define OUT_RES (BRR*3)  // 105168

typedef __attribute__((ext_vector_type(8))) _Float16 half8;
typedef __attribute__((ext_vector_type(4))) float f32x4;

// ---------------- degree histogram ----------------
__global__ void k_hist(const int* __restrict__ row, int* __restrict__ deg, int nE){
  int i = blockIdx.x*blockDim.x + threadIdx.x;
  int st = gridDim.x*blockDim.x;
  for (; i < nE; i += st) atomicAdd(&deg[row[i]], 1);
}

// ---------------- exclusive scan (3-phase for N); also emits dinv ----------------
__global__ void k_scan1(const int* __restrict__ deg, int* __restrict__ rowptr,
                        int* __restrict__ partials, float* __restrict__ dinv){
  __shared__ int s[256];
  int t = threadIdx.x; int i = blockIdx.x*256 + t;
  int v = deg[i]; s[t] = v; __syncthreads();
  dinv[i] = v > 0 ? 1.0f/sqrtf((float)v) : 0.0f;
  for (int off = 1; off < 256; off <<= 1){
    int x = (t >= off) ? s[t-off] : 0; __syncthreads();
    s[t] += x; __syncthreads();
  }
  rowptr[i] = s[t] - v;
  if (t == 255) partials[blockIdx.x] = s[255];
}

__global__ void k_scan2(int* __restrict__ partials){
  __shared__ int s[1024];
  int t = threadIdx.x; int v = partials[t]; s[t] = v; __syncthreads();
  for (int off = 1; off < 1024; off <<= 1){
    int x = (t >= off) ? s[t-off] : 0; __syncthreads();
    s[t] += x; __syncthreads();
  }
  partials[t] = s[t] - v;
}

__global__ void k_scan3(int* __restrict__ rowptr, const int* __restrict__ partials){
  int t = threadIdx.x; int i = blockIdx.x*256 + t;
  rowptr[i] += partials[blockIdx.x];
  if (i == 0) rowptr[NN] = NE;
}

// single-block scan for the small ref graph; also emits dinvR
__global__ void k_scan_small(const int* __restrict__ deg, int* __restrict__ rowptr,
                             float* __restrict__ dinv, int n){
  __shared__ int s[256];
  int t = threadIdx.x;
  int carry = 0;
  for (int base = 0; base < n; base += 256){
    int idx = base + t;
    int v = (idx < n) ? deg[idx] : 0;
    if (idx < n) dinv[idx] = v > 0 ? 1.0f/sqrtf((float)v) : 0.0f;
    s[t] = v; __syncthreads();
    for (int off = 1; off < 256; off <<= 1){
      int x = (t >= off) ? s[t-off] : 0; __syncthreads();
      s[t] += x; __syncthreads();
    }
    if (idx < n) rowptr[idx] = carry + s[t] - v;
    carry += s[255];
    __syncthreads();
  }
  if (t == 0) rowptr[n] = carry;
}

// ---------------- CSR scatter (packed int2 {col, w}) ----------------
__global__ void k_scatter(const int* __restrict__ row, const int* __restrict__ col,
                          const float* __restrict__ dinv, const int* __restrict__ rowptr,
                          int* __restrict__ cursor, int2* __restrict__ pair, int nE){
  int i = blockIdx.x*blockDim.x + threadIdx.x;
  int st = gridDim.x*blockDim.x;
  for (; i < nE; i += st){
    int r = row[i], c = col[i];
    int pos = rowptr[r] + atomicAdd(&cursor[r], 1);
    pair[pos] = make_int2(c, __float_as_int(-dinv[r]*dinv[c]));
  }
}

// ---------------- pad [n,3] f32 -> [n] float4 ----------------
__global__ void k_pad3(const float* __restrict__ src, float4* __restrict__ dst, int n){
  int i = blockIdx.x*blockDim.x + threadIdx.x;
  if (i < n) dst[i] = make_float4(src[i*3], src[i*3+1], src[i*3+2], 0.0f);
}

// ---------------- prop 3-ch f32, padded float4, unroll 4 ----------------
__global__ void k_prop3p(const float4* __restrict__ h, float4* __restrict__ y,
                         const int* __restrict__ rowptr, const int2* __restrict__ pair, int n){
  int i = blockIdx.x*blockDim.x + threadIdx.x;
  if (i >= n) return;
  float a0 = 0.f, a1 = 0.f, a2 = 0.f;
  int s = rowptr[i], e = rowptr[i+1];
  int p = s;
  for (; p + 4 <= e; p += 4){
    int2 q0 = pair[p], q1 = pair[p+1], q2 = pair[p+2], q3 = pair[p+3];
    float4 v0 = h[q0.x], v1 = h[q1.x], v2 = h[q2.x], v3 = h[q3.x];
    float w0 = __int_as_float(q0.y), w1 = __int_as_float(q1.y);
    float w2 = __int_as_float(q2.y), w3 = __int_as_float(q3.y);
    a0 = fmaf(w0,v0.x, fmaf(w1,v1.x, fmaf(w2,v2.x, fmaf(w3,v3.x, a0))));
    a1 = fmaf(w0,v0.y, fmaf(w1,v1.y, fmaf(w2,v2.y, fmaf(w3,v3.y, a1))));
    a2 = fmaf(w0,v0.z, fmaf(w1,v1.z, fmaf(w2,v2.z, fmaf(w3,v3.z, a2))));
  }
  for (; p < e; p++){
    int2 q = pair[p]; float wv = __int_as_float(q.y);
    float4 v = h[q.x];
    a0 = fmaf(wv, v.x, a0); a1 = fmaf(wv, v.y, a1); a2 = fmaf(wv, v.z, a2);
  }
  y[i] = make_float4(a0, a1, a2, 0.0f);
}

// ---------------- f32 64-ch prop (ref stack only, packed pairs) ----------------
__global__ void k_prop64(const float* __restrict__ h, float* __restrict__ y,
                         const int* __restrict__ rowptr, const int2* __restrict__ pair, int n){
  int t = threadIdx.x, lane = t & 63;
  int i = blockIdx.x*4 + (t >> 6);
  if (i >= n) return;
  float acc = 0.f;
  int s = rowptr[i], e = rowptr[i+1];
  int p = s;
  for (; p + 4 <= e; p += 4){
    int2 q0 = pair[p], q1 = pair[p+1], q2 = pair[p+2], q3 = pair[p+3];
    float v0 = h[(size_t)q0.x*64 + lane], v1 = h[(size_t)q1.x*64 + lane];
    float v2 = h[(size_t)q2.x*64 + lane], v3 = h[(size_t)q3.x*64 + lane];
    acc = fmaf(__int_as_float(q0.y),v0, fmaf(__int_as_float(q1.y),v1,
          fmaf(__int_as_float(q2.y),v2, fmaf(__int_as_float(q3.y),v3, acc))));
  }
  for (; p < e; p++){
    int2 q = pair[p];
    acc = fmaf(__int_as_float(q.y), h[(size_t)q.x*64 + lane], acc);
  }
  y[(size_t)i*64 + lane] = acc;
}

// ---------------- f16 64-ch prop: 8 lanes/row (16B dwordx4 each), unroll 8 -----
__global__ void __launch_bounds__(256) k_prop64h(
    const uint4* __restrict__ h4, uint4* __restrict__ y4,
    const int* __restrict__ rowptr, const int2* __restrict__ pair, int n){
  int t = threadIdx.x;
  int sub = t & 7;                      // 16B chunk within the 128B row
  int row = blockIdx.x*32 + (t >> 3);
  if (row >= n) return;
  int s = rowptr[row], e = rowptr[row+1];
  float ac[8];
  #pragma unroll
  for (int k = 0; k < 8; k++) ac[k] = 0.f;
  int p = s;
  for (; p + 8 <= e; p += 8){
    int2 q[8]; uint4 v[8];
    #pragma unroll
    for (int j = 0; j < 8; j++) q[j] = pair[p+j];
    #pragma unroll
    for (int j = 0; j < 8; j++) v[j] = h4[(size_t)q[j].x*8 + sub];
    #pragma unroll
    for (int j = 0; j < 8; j++){
      float wv = __int_as_float(q[j].y);
      #pragma unroll
      for (int k = 0; k < 4; k++){
        float2 f = __half22float2(((const __half2*)&v[j])[k]);
        ac[2*k]   = fmaf(wv, f.x, ac[2*k]);
        ac[2*k+1] = fmaf(wv, f.y, ac[2*k+1]);
      }
    }
  }
  for (; p + 4 <= e; p += 4){
    int2 q[4]; uint4 v[4];
    #pragma unroll
    for (int j = 0; j < 4; j++) q[j] = pair[p+j];
    #pragma unroll
    for (int j = 0; j < 4; j++) v[j] = h4[(size_t)q[j].x*8 + sub];
    #pragma unroll
    for (int j = 0; j < 4; j++){
      float wv = __int_as_float(q[j].y);
      #pragma unroll
      for (int k = 0; k < 4; k++){
        float2 f = __half22float2(((const __half2*)&v[j])[k]);
        ac[2*k]   = fmaf(wv, f.x, ac[2*k]);
        ac[2*k+1] = fmaf(wv, f.y, ac[2*k+1]);
      }
    }
  }
  for (; p < e; p++){
    int2 q = pair[p];
    float wv = __int_as_float(q.y);
    uint4 v = h4[(size_t)q.x*8 + sub];
    #pragma unroll
    for (int k = 0; k < 4; k++){
      float2 f = __half22float2(((const __half2*)&v)[k]);
      ac[2*k]   = fmaf(wv, f.x, ac[2*k]);
      ac[2*k+1] = fmaf(wv, f.y, ac[2*k+1]);
    }
  }
  uint4 r;
  #pragma unroll
  for (int k = 0; k < 4; k++){
    __half2 hp = __floats2half2_rn(ac[2*k], ac[2*k+1]);
    ((unsigned*)&r)[k] = *(unsigned*)&hp;
  }
  y4[(size_t)row*8 + sub] = r;
}

// ---------------- Cheb combine, layer-1 (3 input channels, padded float4 in) ---
__global__ void k_combine3f(const float4* __restrict__ x, const float4* __restrict__ t1,
                            const float4* __restrict__ t2, const float* __restrict__ W,
                            const float* __restrict__ bias, float* __restrict__ out, int n){
  int t = threadIdx.x, lane = t & 63;
  int i = blockIdx.x*4 + (t >> 6);
  if (i >= n) return;
  float4 px = x[i], p1 = t1[i], p2 = t2[i];
  const float* fx = (const float*)&px;
  const float* f1 = (const float*)&p1;
  const float* f2 = (const float*)&p2;
  float acc = bias[lane];
  #pragma unroll
  for (int j = 0; j < 3; j++){
    float x0 = fx[j], x1 = f1[j];
    float x2 = 2.0f*f2[j] - x0;
    acc += x0*W[      j*64 + lane]
         + x1*W[192 + j*64 + lane]
         + x2*W[384 + j*64 + lane];
  }
  out[(size_t)i*64 + lane] = tanhf(acc);
}

__global__ void k_combine3h(const float4* __restrict__ x, const float4* __restrict__ t1,
                            const float4* __restrict__ t2, const float* __restrict__ W,
                            const float* __restrict__ bias, __half* __restrict__ out, int n){
  int t = threadIdx.x, lane = t & 63;
  int i = blockIdx.x*4 + (t >> 6);
  if (i >= n) return;
  float4 px = x[i], p1 = t1[i], p2 = t2[i];
  const float* fx = (const float*)&px;
  const float* f1 = (const float*)&p1;
  const float* f2 = (const float*)&p2;
  float acc = bias[lane];
  #pragma unroll
  for (int j = 0; j < 3; j++){
    float x0 = fx[j], x1 = f1[j];
    float x2 = 2.0f*f2[j] - x0;
    acc += x0*W[      j*64 + lane]
         + x1*W[192 + j*64 + lane]
         + x2*W[384 + j*64 + lane];
  }
  out[(size_t)i*64 + lane] = __float2half_rn(tanhf(acc));
}

// ---------------- effective weights: {W0 - W2, W1, 2*W2} (f32) ----------------
__global__ void k_weff(const float* __restrict__ W, float* __restrict__ D){
  int i = blockIdx.x*blockDim.x + threadIdx.x;  // 4096 threads
  D[i]        = W[i] - W[8192 + i];
  D[4096 + i] = W[4096 + i];
  D[8192 + i] = 2.0f * W[8192 + i];
}

// ---------------- pack layer-2 weights into MFMA B-fragments (f16) -----------
__global__ void k_wpack(const float* __restrict__ W, _Float16* __restrict__ D){
  int t = blockIdx.x*blockDim.x + threadIdx.x;   // 12288
  int reg = t & 7, lane = (t >> 3) & 63, nt = (t >> 9) & 3, kc = t >> 11;
  int m = kc >> 1;
  int kin = (kc & 1)*32 + ((lane >> 4) & 3)*8 + reg;
  int n = nt*16 + (lane & 15);
  float eff;
  if      (m == 0) eff = W[kin*64 + n] - W[8192 + kin*64 + n];
  else if (m == 1) eff = W[4096 + kin*64 + n];
  else             eff = 2.0f * W[8192 + kin*64 + n];
  D[t] = (_Float16)eff;
}

// ---------------- MFMA Cheb combine (layer 2) ----------------
__global__ void __launch_bounds__(256) k_combine64m(
    const __half* A, const __half* B, const __half* C,
    const _Float16* __restrict__ wfrag, const float* __restrict__ bias,
    __half* out, int ntiles, int wavestride){
  int t = threadIdx.x;
  int lane = t & 63;
  int wv = blockIdx.x*4 + (t >> 6);
  half8 bf[24];
  #pragma unroll
  for (int i = 0; i < 24; i++)
    bf[i] = *(const half8*)(wfrag + ((size_t)(i*64 + lane))*8);
  int col = lane & 15, grp = (lane >> 4) & 3;
  float b0 = bias[col], b1 = bias[16+col], b2 = bias[32+col], b3 = bias[48+col];
  for (int tile = wv; tile < ntiles; tile += wavestride){
    size_t rb = (size_t)tile*16;
    f32x4 acc0 = {b0,b0,b0,b0}, acc1 = {b1,b1,b1,b1};
    f32x4 acc2 = {b2,b2,b2,b2}, acc3 = {b3,b3,b3,b3};
    #pragma unroll
    for (int kc = 0; kc < 6; kc++){
      const __half* s = (kc < 2) ? A : (kc < 4) ? B : C;
      half8 a = *(const half8*)(s + (rb + col)*64 + (kc & 1)*32 + grp*8);
      acc0 = __builtin_amdgcn_mfma_f32_16x16x32_f16(a, bf[kc*4+0], acc0, 0,0,0);
      acc1 = __builtin_amdgcn_mfma_f32_16x16x32_f16(a, bf[kc*4+1], acc1, 0,0,0);
      acc2 = __builtin_amdgcn_mfma_f32_16x16x32_f16(a, bf[kc*4+2], acc2, 0,0,0);
      acc3 = __builtin_amdgcn_mfma_f32_16x16x32_f16(a, bf[kc*4+3], acc3, 0,0,0);
    }
    __half* o = out + (rb + grp*4)*64;
    #pragma unroll
    for (int r = 0; r < 4; r++){
      o[(size_t)r*64 +      col] = __float2half_rn(tanhf(acc0[r]));
      o[(size_t)r*64 + 16 + col] = __float2half_rn(tanhf(acc1[r]));
      o[(size_t)r*64 + 32 + col] = __float2half_rn(tanhf(acc2[r]));
      o[(size_t)r*64 + 48 + col] = __float2half_rn(tanhf(acc3[r]));
    }
  }
}

// ---------------- segment sums of 3 f16 buffers ----------------
__global__ void k_pool3(const __half2* __restrict__ hA, const __half2* __restrict__ hB,
                        const __half2* __restrict__ hC, float* __restrict__ pA,
                        float* __restrict__ pB, float* __restrict__ pC){
  const __half2* src = (blockIdx.y == 0) ? hA : (blockIdx.y == 1) ? hB : hC;
  float* dst         = (blockIdx.y == 0) ? pA : (blockIdx.y == 1) ? pB : pC;
  int blk = blockIdx.x;                 // 512: seg*16 + chunk
  int chunk = blk & 15, seg = blk >> 4;
  int t = threadIdx.x, ch2 = t & 31, rsub = t >> 5;
  int base = seg*8192 + chunk*512;
  float ax = 0.f, ay = 0.f;
  for (int j = 0; j < 64; j++){
    int row = base + rsub + j*8;
    float2 v = __half22float2(src[(size_t)row*32 + ch2]);
    ax += v.x; ay += v.y;
  }
  __shared__ float sx[256], sy[256];
  sx[t] = ax; sy[t] = ay; __syncthreads();
  if (t < 32){
    float tx = 0.f, ty = 0.f;
    #pragma unroll
    for (int j = 0; j < 8; j++){ tx += sx[ch2 + j*32]; ty += sy[ch2 + j*32]; }
    int b = seg >> 1, half_ = seg & 1;
    atomicAdd(&dst[half_*1024 + b*64 + ch2*2],     tx);
    atomicAdd(&dst[half_*1024 + b*64 + ch2*2 + 1], ty);
  }
}

// ---------------- pooled layer-3 combine ----------------
__global__ void k_combine_pooled(const float* __restrict__ pA, const float* __restrict__ pB,
                                 const float* __restrict__ pC, const float* __restrict__ weff,
                                 const float* __restrict__ bias, float* __restrict__ xbbsc,
                                 float* __restrict__ dout){
  int i = blockIdx.x*blockDim.x + threadIdx.x;   // 2048
  int pr = i >> 6, c = i & 63;
  const float* a = pA + pr*64;
  const float* b = pB + pr*64;
  const float* cc = pC + pr*64;
  float v = 0.f;
  for (int k = 0; k < 64; k++){
    v = fmaf(a[k],  weff[        k*64 + c], v);
    v = fmaf(b[k],  weff[4096 +  k*64 + c], v);
    v = fmaf(cc[k], weff[8192 +  k*64 + c], v);
  }
  v = v*(1.0f/8192.0f) + bias[c];
  xbbsc[i] = v;
  dout[OUT_RES + i] = v;
}

// ---------------- Cheb combine 64-ch, f32 (ref stack) ----------------
__global__ void __launch_bounds__(256) k_combine64f(
    const float* __restrict__ A, const float* __restrict__ Bm, const float* __restrict__ C,
    const float* __restrict__ Weff, const float* __restrict__ bias,
    float* __restrict__ out, int n){
  int t = threadIdx.x;
  int lane = t & 63;
  int wid  = __builtin_amdgcn_readfirstlane(t >> 6);
  int half_ = wid & 1;
  int row  = blockIdx.x*128 + (wid >> 1)*64 + lane;
  bool active = (row < n);
  float acc[32];
  #pragma unroll
  for (int c = 0; c < 32; c++) acc[c] = bias[half_*32 + c];
  if (active){
    #pragma unroll 1
    for (int m = 0; m < 3; m++){
      const float* src = (m == 0 ? A : (m == 1 ? Bm : C)) + (size_t)row*64;
      const float* Wm  = Weff + m*4096 + half_*32;
      #pragma unroll 1
      for (int k4 = 0; k4 < 16; k4++){
        float4 a4 = *(const float4*)(src + k4*4);
        const float* wk = Wm + k4*256;
        #pragma unroll
        for (int kk = 0; kk < 4; kk++){
          float a = (kk == 0) ? a4.x : (kk == 1) ? a4.y : (kk == 2) ? a4.z : a4.w;
          #pragma unroll
          for (int c = 0; c < 32; c++)
            acc[c] = fmaf(a, wk[kk*64 + c], acc[c]);
        }
      }
    }
  }
  __syncthreads();
  if (active){
    float* o = out + (size_t)row*64 + half_*32;
    #pragma unroll
    for (int c = 0; c < 32; c++) o[c] = tanhf(acc[c]);
  }
}

// ---------------- fused row-local matmul chain (ref side): 3 matmuls ----------
__global__ void k_refchain(const float* __restrict__ refA, const float* __restrict__ mlp_w,
                           const float* __restrict__ mlp2_w, const float* __restrict__ rep0_w,
                           float* __restrict__ rt3a, int n){
  int t = threadIdx.x, lane = t & 63;
  int i = blockIdx.x*4 + (t >> 6);
  if (i >= n) return;
  float v = refA[i*64 + lane];
  float a = 0.f;
  #pragma unroll
  for (int k = 0; k < 64; k++) a += __shfl(v, k, 64) * mlp_w[k*64 + lane];
  float b = 0.f;
  #pragma unroll
  for (int k = 0; k < 64; k++) b += __shfl(a, k, 64) * mlp2_w[k*64 + lane];
  float c = 0.f;
  #pragma unroll
  for (int k = 0; k < 64; k++) c += __shfl(b, k, 64) * rep0_w[k*64 + lane];
  rt3a[i*64 + lane] = c;
}

// ---------------- fused row-local chain (batch side): bb/sc terms -------------
__global__ void k_bbchain(const float* __restrict__ xbbsc,
                          const float* __restrict__ mlp_w,  const float* __restrict__ mlp_b,
                          const float* __restrict__ mlp2_w, const float* __restrict__ mlp2_b,
                          const float* __restrict__ rep0_w, const float* __restrict__ rep0_b,
                          float* __restrict__ bt3a){
  int t = threadIdx.x, lane = t & 63;
  int i = blockIdx.x*4 + (t >> 6);
  if (i >= NB) return;
  float vbb = xbbsc[i*64 + lane];
  float vsc = xbbsc[1024 + i*64 + lane];
  float a = mlp_b[lane];
  #pragma unroll
  for (int k = 0; k < 64; k++) a += __shfl(vbb, k, 64) * mlp_w[4096 + k*64 + lane];
  float b = mlp2_b[lane];
  #pragma unroll
  for (int k = 0; k < 64; k++) b += __shfl(a, k, 64) * mlp2_w[k*64 + lane];
  #pragma unroll
  for (int k = 0; k < 64; k++) b += __shfl(vsc, k, 64) * mlp2_w[4096 + k*64 + lane];
  float c = rep0_b[lane];
  #pragma unroll
  for (int k = 0; k < 64; k++) c += __shfl(b, k, 64) * rep0_w[k*64 + lane];
  bt3a[i*64 + lane] = c;
}

// ---------------- final: relu(rt3[r]+bt3[b]) -> rep1+relu -> rep2+relu ----------------
__global__ void k_final(const float* __restrict__ rt3, const float* __restrict__ bt3,
                        const float* __restrict__ W1, const float* __restrict__ b1,
                        const float* __restrict__ W2, const float* __restrict__ b2,
                        float* __restrict__ dout){
  int t = threadIdx.x, lane = t & 63;
  int g = blockIdx.x*4 + (t >> 6);
  if (g >= BRR) return;
  int b = g / RR, r = g - b*RR;
  float m = rt3[r*64 + lane] + bt3[b*64 + lane];
  m = fmaxf(m, 0.0f);
  float acc = b1[lane];
  #pragma unroll
  for (int k = 0; k < 64; k++) acc += __shfl(m, k, 64) * W1[k*64 + lane];
  float u = fmaxf(acc, 0.0f);
  float p0 = u*W2[lane*3+0], p1 = u*W2[lane*3+1], p2 = u*W2[lane*3+2];
  #pragma unroll
  for (int off = 32; off > 0; off >>= 1){
    p0 += __shfl_xor(p0, off, 64);
    p1 += __shfl_xor(p1, off, 64);
    p2 += __shfl_xor(p2, off, 64);
  }
  if (lane == 0){
    dout[g*3+0] = fmaxf(p0 + b2[0], 0.0f);
    dout[g*3+1] = fmaxf(p1 + b2[1], 0.0f);
    dout[g*3+2] = fmaxf(p2 + b2[2], 0.0f);
  }
}

extern "C" void kernel_launch(void* const* d_in, const int* in_sizes, int n_in,
                              void* d_out, int out_size, void* d_ws, size_t ws_size,
                              hipStream_t stream){
  const float* x     = (const float*)d_in[0];
  const int*   eidx  = (const int*)d_in[1];   // [2,E] flat: rows then cols
  const float* x_ref = (const float*)d_in[4];
  const int*   eref  = (const int*)d_in[5];   // [2,ER]
  const float* cw0 = (const float*)d_in[6],  *cb0 = (const float*)d_in[7];
  const float* cw1 = (const float*)d_in[8],  *cb1 = (const float*)d_in[9];
  const float* cw2 = (const float*)d_in[10], *cb2 = (const float*)d_in[11];
  const float* rw0 = (const float*)d_in[12], *rb0 = (const float*)d_in[13];
  const float* rw1 = (const float*)d_in[14], *rb1 = (const float*)d_in[15];
  const float* rw2 = (const float*)d_in[16], *rb2 = (const float*)d_in[17];
  const float* mlp_w  = (const float*)d_in[18], *mlp_b  = (const float*)d_in[19];
  const float* mlp2_w = (const float*)d_in[20], *mlp2_b = (const float*)d_in[21];
  const float* rep0_w = (const float*)d_in[22], *rep0_b = (const float*)d_in[23];
  const float* rep1_w = (const float*)d_in[24], *rep1_b = (const float*)d_in[25];
  const float* rep2_w = (const float*)d_in[26], *rep2_b = (const float*)d_in[27];
  float* out = (float*)d_out;

  // ---- workspace allocator (256B aligned) ----
  char* w = (char*)d_ws;
  size_t off = 0;
  auto alloc = [&](size_t bytes)->void*{
    void* p = w + off;
    off = (off + bytes + 255) & ~(size_t)255;
    return p;
  };
  // zero zone (single memset): deg, cursor, degR, cursorR, pooled sums
  int*   deg     = (int*)  alloc(NN*4);
  int*   cursor  = (int*)  alloc(NN*4);
  int*   degR    = (int*)  alloc(RR*4);
  int*   cursorR = (int*)  alloc(RR*4);
  float* poolA   = (float*)alloc(2048*4);
  float* poolB   = (float*)alloc(2048*4);
  float* poolC   = (float*)alloc(2048*4);
  size_t zero_bytes = off;

  int*   rowptr   = (int*)  alloc((NN+1)*4);
  int*   partials = (int*)  alloc(1024*4);
  int*   rowptrR  = (int*)  alloc((RR+1)*4);
  float* dinv     = (float*)alloc(NN*4);
  float* dinvR    = (float*)alloc(RR*4);
  int2*  cpair    = (int2*) alloc((size_t)NE*8);
  int2*  cpairR   = (int2*) alloc((size_t)ER*8);
  float4* x4      = (float4*)alloc((size_t)NN*16);
  float4* t1_4    = (float4*)alloc((size_t)NN*16);
  float4* t2_4    = (float4*)alloc((size_t)NN*16);
  float4* xr4     = (float4*)alloc((size_t)RR*16);
  float4* rt1_4   = (float4*)alloc((size_t)RR*16);
  float4* rt2_4   = (float4*)alloc((size_t)RR*16);
  __half* hA      = (__half*)alloc((size_t)NN*64*2);
  __half* hB      = (__half*)alloc((size_t)NN*64*2);
  __half* hC      = (__half*)alloc((size_t)NN*64*2);
  float* refA     = (float*)alloc(RR*64*4);
  float* refB     = (float*)alloc(RR*64*4);
  float* refC     = (float*)alloc(RR*64*4);
  float* xbbsc    = (float*)alloc(2048*4);     // [0..1023]=x_bb, [1024..2047]=x_sc
  float* rt3a     = (float*)alloc(RR*64*4);
  float* bt3a     = (float*)alloc(NB*64*4);
  float* weffC2   = (float*)alloc(12288*4);
  float* weffR1   = (float*)alloc(12288*4);
  float* weffR2   = (float*)alloc(12288*4);
  _Float16* wfragC1 = (_Float16*)alloc(12288*2);
  (void)ws_size; (void)in_sizes; (void)n_in; (void)out_size;

  hipMemsetAsync(d_ws, 0, zero_bytes, stream);

  // ---- effective combine weights + input padding ----
  k_weff<<<16, 256, 0, stream>>>(cw2, weffC2);
  k_weff<<<16, 256, 0, stream>>>(rw1, weffR1);
  k_weff<<<16, 256, 0, stream>>>(rw2, weffR2);
  k_wpack<<<48, 256, 0, stream>>>(cw1, wfragC1);
  k_pad3<<<1024, 256, 0, stream>>>(x, x4, NN);
  k_pad3<<<9, 256, 0, stream>>>(x_ref, xr4, RR);

  // ---- CSR build, main + ref (simple scatter; line-alloc floor accepted) ----
  k_hist<<<2048, 256, 0, stream>>>(eidx, deg, NE);
  k_hist<<<64,   256, 0, stream>>>(eref, degR, ER);
  k_scan1<<<1024, 256, 0, stream>>>(deg, rowptr, partials, dinv);
  k_scan2<<<1, 1024, 0, stream>>>(partials);
  k_scan3<<<1024, 256, 0, stream>>>(rowptr, partials);
  k_scan_small<<<1, 256, 0, stream>>>(degR, rowptrR, dinvR, RR);
  k_scatter<<<2048, 256, 0, stream>>>(eidx, eidx+NE, dinv, rowptr, cursor, cpair, NE);
  k_scatter<<<64,   256, 0, stream>>>(eref, eref+ER, dinvR, rowptrR, cursorR, cpairR, ER);

  // ---- main stack layer 1 (3-ch padded f32, f16 out) ----
  k_prop3p<<<1024, 256, 0, stream>>>(x4, t1_4, rowptr, cpair, NN);
  k_prop3p<<<1024, 256, 0, stream>>>(t1_4, t2_4, rowptr, cpair, NN);
  k_combine3h<<<NN/4, 256, 0, stream>>>(x4, t1_4, t2_4, cw0, cb0, hA, NN);
  // ---- layer 2 (f16 features, MFMA combine) ----
  k_prop64h<<<NN/32, 256, 0, stream>>>((const uint4*)hA, (uint4*)hB, rowptr, cpair, NN);
  k_prop64h<<<NN/32, 256, 0, stream>>>((const uint4*)hB, (uint4*)hC, rowptr, cpair, NN);
  k_combine64m<<<1024, 256, 0, stream>>>(hA, hB, hC, wfragC1, cb1, hA, NN/16, 4096);
  // ---- layer 3: props, then pooled (linear) combine ----
  k_prop64h<<<NN/32, 256, 0, stream>>>((const uint4*)hA, (uint4*)hB, rowptr, cpair, NN);
  k_prop64h<<<NN/32, 256, 0, stream>>>((const uint4*)hB, (uint4*)hC, rowptr, cpair, NN);
  k_pool3<<<dim3(512,3), 256, 0, stream>>>((const __half2*)hA, (const __half2*)hB,
                                           (const __half2*)hC, poolA, poolB, poolC);
  k_combine_pooled<<<8, 256, 0, stream>>>(poolA, poolB, poolC, weffC2, cb2, xbbsc, out);

  // ---- reference stack (f32; tanh after every layer incl. last — source bug) ----
  k_prop3p<<<9, 256, 0, stream>>>(xr4, rt1_4, rowptrR, cpairR, RR);
  k_prop3p<<<9, 256, 0, stream>>>(rt1_4, rt2_4, rowptrR, cpairR, RR);
  k_combine3f<<<548, 256, 0, stream>>>(xr4, rt1_4, rt2_4, rw0, rb0, refA, RR);
  k_prop64<<<548, 256, 0, stream>>>(refA, refB, rowptrR, cpairR, RR);
  k_prop64<<<548, 256, 0, stream>>>(refB, refC, rowptrR, cpairR, RR);
  k_combine64f<<<(RR+127)/128, 256, 0, stream>>>(refA, refB, refC, weffR1, rb1, refA, RR);
  k_prop64<<<548, 256, 0, stream>>>(refA, refB, rowptrR, cpairR, RR);
  k_prop64<<<548, 256, 0, stream>>>(refB, refC, rowptrR, cpairR, RR);
  k_combine64f<<<(RR+127)/128, 256, 0, stream>>>(refA, refB, refC, weffR2, rb2, refA, RR);

  // ---- collapsed MLP head (fused row-local chains) ----
  k_refchain<<<548, 256, 0, stream>>>(refA, mlp_w, mlp2_w, rep0_w, rt3a, RR);
  k_bbchain<<<4, 256, 0, stream>>>(xbbsc, mlp_w, mlp_b, mlp2_w, mlp2_b, rep0_w, rep0_b, bt3a);

  k_final<<<(BRR+3)/4, 256, 0, stream>>>(rt3a, bt3a, rep1_w, rep1_b, rep2_w, rep2_b, out);
}

// Round 9
// 724.128 us; speedup vs baseline: 1.2014x; 1.0633x over previous
//
#include <hip/hip_runtime.h>
#include <hip/hip_fp16.h>
#include <math.h>

#define NN 262144        // total nodes
#define NE 2097152       // total edges
#define RR 2191          // ref nodes
#define ER (RR*16)       // ref edges = 35056
#define NB 16            // batch graphs
#define BRR (NB*RR)      // 35056
#define OUT_RES (BRR*3)  // 105168

typedef __attribute__((ext_vector_type(8))) _Float16 half8;
typedef __attribute__((ext_vector_type(4))) float f32x4;

// ---------------- merged histogram (main + ref), emits per-edge rank ----------
__global__ void k_hist2(const int* __restrict__ eM, int* __restrict__ degM,
                        unsigned char* __restrict__ rankM,
                        const int* __restrict__ eR, int* __restrict__ degR,
                        unsigned char* __restrict__ rankR){
  int b = blockIdx.x;
  if (b < 2048){
    for (int i = b*256 + threadIdx.x; i < NE; i += 2048*256){
      int old = atomicAdd(&degM[eM[i]], 1);
      rankM[i] = (unsigned char)old;
    }
  } else {
    for (int i = (b-2048)*256 + threadIdx.x; i < ER; i += 64*256){
      int old = atomicAdd(&degR[eR[i]], 1);
      rankR[i] = (unsigned char)old;
    }
  }
}

// ---------------- exclusive scan (3-phase for N); also emits dinv ----------------
__global__ void k_scan1(const int* __restrict__ deg, int* __restrict__ rowptr,
                        int* __restrict__ partials, float* __restrict__ dinv){
  __shared__ int s[256];
  int t = threadIdx.x; int i = blockIdx.x*256 + t;
  int v = deg[i]; s[t] = v; __syncthreads();
  dinv[i] = v > 0 ? 1.0f/sqrtf((float)v) : 0.0f;
  for (int off = 1; off < 256; off <<= 1){
    int x = (t >= off) ? s[t-off] : 0; __syncthreads();
    s[t] += x; __syncthreads();
  }
  rowptr[i] = s[t] - v;
  if (t == 255) partials[blockIdx.x] = s[255];
}

// merged: block 0 = scan of 1024 partials; block 1 = full ref-graph scan (+dinvR)
__global__ void __launch_bounds__(1024) k_scan2m(int* __restrict__ partials,
                                                 const int* __restrict__ degR,
                                                 int* __restrict__ rowptrR,
                                                 float* __restrict__ dinvR){
  __shared__ int s[1024];
  int t = threadIdx.x;
  if (blockIdx.x == 0){
    int v = partials[t]; s[t] = v; __syncthreads();
    for (int off = 1; off < 1024; off <<= 1){
      int x = (t >= off) ? s[t-off] : 0; __syncthreads();
      s[t] += x; __syncthreads();
    }
    partials[t] = s[t] - v;
  } else {
    int carry = 0;
    for (int base = 0; base < RR; base += 1024){
      int idx = base + t;
      int v = (idx < RR) ? degR[idx] : 0;
      if (idx < RR) dinvR[idx] = v > 0 ? 1.0f/sqrtf((float)v) : 0.0f;
      s[t] = v; __syncthreads();
      for (int off = 1; off < 1024; off <<= 1){
        int x = (t >= off) ? s[t-off] : 0; __syncthreads();
        s[t] += x; __syncthreads();
      }
      if (idx < RR) rowptrR[idx] = carry + s[t] - v;
      carry += s[1023];
      __syncthreads();
    }
    if (t == 0) rowptrR[RR] = carry;
  }
}

__global__ void k_scan3(int* __restrict__ rowptr, const int* __restrict__ partials){
  int t = threadIdx.x; int i = blockIdx.x*256 + t;
  rowptr[i] += partials[blockIdx.x];
  if (i == 0) rowptr[NN] = NE;
}

// ---------------- merged scatter (main + ref), rank-addressed, no atomics ------
__global__ void k_scatter2(const int* __restrict__ eM, const float* __restrict__ dinv,
                           const int* __restrict__ rowptr, const unsigned char* __restrict__ rankM,
                           int2* __restrict__ pair,
                           const int* __restrict__ eR, const float* __restrict__ dinvR,
                           const int* __restrict__ rowptrR, const unsigned char* __restrict__ rankR,
                           int2* __restrict__ pairR){
  int b = blockIdx.x;
  if (b < 2048){
    for (int i = b*256 + threadIdx.x; i < NE; i += 2048*256){
      int r = eM[i], c = eM[NE + i];
      int pos = rowptr[r] + rankM[i];
      unsigned wbits = (unsigned)__float_as_int(-dinv[r]*dinv[c]);
      long long v = (unsigned)c | ((long long)wbits << 32);
      __builtin_nontemporal_store(v, (long long*)(pair + pos));
    }
  } else {
    for (int i = (b-2048)*256 + threadIdx.x; i < ER; i += 64*256){
      int r = eR[i], c = eR[ER + i];
      int pos = rowptrR[r] + rankR[i];
      unsigned wbits = (unsigned)__float_as_int(-dinvR[r]*dinvR[c]);
      long long v = (unsigned)c | ((long long)wbits << 32);
      __builtin_nontemporal_store(v, (long long*)(pairR + pos));
    }
  }
}

// ---------------- merged prep: weff x3, wpack, pad x4/xr4 ----------------
__global__ void k_prep(const float* __restrict__ cw1, const float* __restrict__ cw2,
                       const float* __restrict__ rw1, const float* __restrict__ rw2,
                       float* __restrict__ weffC2, float* __restrict__ weffR1,
                       float* __restrict__ weffR2, _Float16* __restrict__ wfragC1,
                       const float* __restrict__ x, float4* __restrict__ x4,
                       const float* __restrict__ x_ref, float4* __restrict__ xr4){
  int y = blockIdx.y;
  int i = blockIdx.x*blockDim.x + threadIdx.x;
  if (y < 3){
    if (i < 4096){
      const float* W = (y == 0) ? cw2 : (y == 1) ? rw1 : rw2;
      float* D       = (y == 0) ? weffC2 : (y == 1) ? weffR1 : weffR2;
      D[i]        = W[i] - W[8192 + i];
      D[4096 + i] = W[4096 + i];
      D[8192 + i] = 2.0f * W[8192 + i];
    }
  } else if (y == 3){
    if (i < 12288){
      int reg = i & 7, lane = (i >> 3) & 63, nt = (i >> 9) & 3, kc = i >> 11;
      int m = kc >> 1;
      int kin = (kc & 1)*32 + ((lane >> 4) & 3)*8 + reg;
      int n = nt*16 + (lane & 15);
      float eff;
      if      (m == 0) eff = cw1[kin*64 + n] - cw1[8192 + kin*64 + n];
      else if (m == 1) eff = cw1[4096 + kin*64 + n];
      else             eff = 2.0f * cw1[8192 + kin*64 + n];
      wfragC1[i] = (_Float16)eff;
    }
  } else if (y == 4){
    if (i < NN) x4[i] = make_float4(x[i*3], x[i*3+1], x[i*3+2], 0.0f);
  } else {
    if (i < RR) xr4[i] = make_float4(x_ref[i*3], x_ref[i*3+1], x_ref[i*3+2], 0.0f);
  }
}

// ---------------- prop 3-ch f32, padded float4, unroll 4 ----------------
__global__ void k_prop3p(const float4* __restrict__ h, float4* __restrict__ y,
                         const int* __restrict__ rowptr, const int2* __restrict__ pair, int n){
  int i = blockIdx.x*blockDim.x + threadIdx.x;
  if (i >= n) return;
  float a0 = 0.f, a1 = 0.f, a2 = 0.f;
  int s = rowptr[i], e = rowptr[i+1];
  int p = s;
  for (; p + 4 <= e; p += 4){
    int2 q0 = pair[p], q1 = pair[p+1], q2 = pair[p+2], q3 = pair[p+3];
    float4 v0 = h[q0.x], v1 = h[q1.x], v2 = h[q2.x], v3 = h[q3.x];
    float w0 = __int_as_float(q0.y), w1 = __int_as_float(q1.y);
    float w2 = __int_as_float(q2.y), w3 = __int_as_float(q3.y);
    a0 = fmaf(w0,v0.x, fmaf(w1,v1.x, fmaf(w2,v2.x, fmaf(w3,v3.x, a0))));
    a1 = fmaf(w0,v0.y, fmaf(w1,v1.y, fmaf(w2,v2.y, fmaf(w3,v3.y, a1))));
    a2 = fmaf(w0,v0.z, fmaf(w1,v1.z, fmaf(w2,v2.z, fmaf(w3,v3.z, a2))));
  }
  for (; p < e; p++){
    int2 q = pair[p]; float wv = __int_as_float(q.y);
    float4 v = h[q.x];
    a0 = fmaf(wv, v.x, a0); a1 = fmaf(wv, v.y, a1); a2 = fmaf(wv, v.z, a2);
  }
  y[i] = make_float4(a0, a1, a2, 0.0f);
}

// ---------------- f32 64-ch prop (ref stack only, packed pairs) ----------------
__global__ void k_prop64(const float* __restrict__ h, float* __restrict__ y,
                         const int* __restrict__ rowptr, const int2* __restrict__ pair, int n){
  int t = threadIdx.x, lane = t & 63;
  int i = blockIdx.x*4 + (t >> 6);
  if (i >= n) return;
  float acc = 0.f;
  int s = rowptr[i], e = rowptr[i+1];
  int p = s;
  for (; p + 4 <= e; p += 4){
    int2 q0 = pair[p], q1 = pair[p+1], q2 = pair[p+2], q3 = pair[p+3];
    float v0 = h[(size_t)q0.x*64 + lane], v1 = h[(size_t)q1.x*64 + lane];
    float v2 = h[(size_t)q2.x*64 + lane], v3 = h[(size_t)q3.x*64 + lane];
    acc = fmaf(__int_as_float(q0.y),v0, fmaf(__int_as_float(q1.y),v1,
          fmaf(__int_as_float(q2.y),v2, fmaf(__int_as_float(q3.y),v3, acc))));
  }
  for (; p < e; p++){
    int2 q = pair[p];
    acc = fmaf(__int_as_float(q.y), h[(size_t)q.x*64 + lane], acc);
  }
  y[(size_t)i*64 + lane] = acc;
}

// ---------------- f16 64-ch prop: 8 lanes/row (16B dwordx4 each), unroll 8 -----
__global__ void __launch_bounds__(256) k_prop64h(
    const uint4* __restrict__ h4, uint4* __restrict__ y4,
    const int* __restrict__ rowptr, const int2* __restrict__ pair, int n){
  int t = threadIdx.x;
  int sub = t & 7;                      // 16B chunk within the 128B row
  int row = blockIdx.x*32 + (t >> 3);
  if (row >= n) return;
  int s = rowptr[row], e = rowptr[row+1];
  float ac[8];
  #pragma unroll
  for (int k = 0; k < 8; k++) ac[k] = 0.f;
  int p = s;
  for (; p + 8 <= e; p += 8){
    int2 q[8]; uint4 v[8];
    #pragma unroll
    for (int j = 0; j < 8; j++) q[j] = pair[p+j];
    #pragma unroll
    for (int j = 0; j < 8; j++) v[j] = h4[(size_t)q[j].x*8 + sub];
    #pragma unroll
    for (int j = 0; j < 8; j++){
      float wv = __int_as_float(q[j].y);
      #pragma unroll
      for (int k = 0; k < 4; k++){
        float2 f = __half22float2(((const __half2*)&v[j])[k]);
        ac[2*k]   = fmaf(wv, f.x, ac[2*k]);
        ac[2*k+1] = fmaf(wv, f.y, ac[2*k+1]);
      }
    }
  }
  for (; p + 4 <= e; p += 4){
    int2 q[4]; uint4 v[4];
    #pragma unroll
    for (int j = 0; j < 4; j++) q[j] = pair[p+j];
    #pragma unroll
    for (int j = 0; j < 4; j++) v[j] = h4[(size_t)q[j].x*8 + sub];
    #pragma unroll
    for (int j = 0; j < 4; j++){
      float wv = __int_as_float(q[j].y);
      #pragma unroll
      for (int k = 0; k < 4; k++){
        float2 f = __half22float2(((const __half2*)&v[j])[k]);
        ac[2*k]   = fmaf(wv, f.x, ac[2*k]);
        ac[2*k+1] = fmaf(wv, f.y, ac[2*k+1]);
      }
    }
  }
  for (; p < e; p++){
    int2 q = pair[p];
    float wv = __int_as_float(q.y);
    uint4 v = h4[(size_t)q.x*8 + sub];
    #pragma unroll
    for (int k = 0; k < 4; k++){
      float2 f = __half22float2(((const __half2*)&v)[k]);
      ac[2*k]   = fmaf(wv, f.x, ac[2*k]);
      ac[2*k+1] = fmaf(wv, f.y, ac[2*k+1]);
    }
  }
  uint4 r;
  #pragma unroll
  for (int k = 0; k < 4; k++){
    __half2 hp = __floats2half2_rn(ac[2*k], ac[2*k+1]);
    ((unsigned*)&r)[k] = *(unsigned*)&hp;
  }
  y4[(size_t)row*8 + sub] = r;
}

// ---------------- Cheb combine, layer-1 (3 input channels, padded float4 in) ---
__global__ void k_combine3f(const float4* __restrict__ x, const float4* __restrict__ t1,
                            const float4* __restrict__ t2, const float* __restrict__ W,
                            const float* __restrict__ bias, float* __restrict__ out, int n){
  int t = threadIdx.x, lane = t & 63;
  int i = blockIdx.x*4 + (t >> 6);
  if (i >= n) return;
  float4 px = x[i], p1 = t1[i], p2 = t2[i];
  const float* fx = (const float*)&px;
  const float* f1 = (const float*)&p1;
  const float* f2 = (const float*)&p2;
  float acc = bias[lane];
  #pragma unroll
  for (int j = 0; j < 3; j++){
    float x0 = fx[j], x1 = f1[j];
    float x2 = 2.0f*f2[j] - x0;
    acc += x0*W[      j*64 + lane]
         + x1*W[192 + j*64 + lane]
         + x2*W[384 + j*64 + lane];
  }
  out[(size_t)i*64 + lane] = tanhf(acc);
}

__global__ void k_combine3h(const float4* __restrict__ x, const float4* __restrict__ t1,
                            const float4* __restrict__ t2, const float* __restrict__ W,
                            const float* __restrict__ bias, __half* __restrict__ out, int n){
  int t = threadIdx.x, lane = t & 63;
  int i = blockIdx.x*4 + (t >> 6);
  if (i >= n) return;
  float4 px = x[i], p1 = t1[i], p2 = t2[i];
  const float* fx = (const float*)&px;
  const float* f1 = (const float*)&p1;
  const float* f2 = (const float*)&p2;
  float acc = bias[lane];
  #pragma unroll
  for (int j = 0; j < 3; j++){
    float x0 = fx[j], x1 = f1[j];
    float x2 = 2.0f*f2[j] - x0;
    acc += x0*W[      j*64 + lane]
         + x1*W[192 + j*64 + lane]
         + x2*W[384 + j*64 + lane];
  }
  out[(size_t)i*64 + lane] = __float2half_rn(tanhf(acc));
}

// ---------------- MFMA Cheb combine (layer 2) ----------------
__global__ void __launch_bounds__(256) k_combine64m(
    const __half* A, const __half* B, const __half* C,
    const _Float16* __restrict__ wfrag, const float* __restrict__ bias,
    __half* out, int ntiles, int wavestride){
  int t = threadIdx.x;
  int lane = t & 63;
  int wv = blockIdx.x*4 + (t >> 6);
  half8 bf[24];
  #pragma unroll
  for (int i = 0; i < 24; i++)
    bf[i] = *(const half8*)(wfrag + ((size_t)(i*64 + lane))*8);
  int col = lane & 15, grp = (lane >> 4) & 3;
  float b0 = bias[col], b1 = bias[16+col], b2 = bias[32+col], b3 = bias[48+col];
  for (int tile = wv; tile < ntiles; tile += wavestride){
    size_t rb = (size_t)tile*16;
    f32x4 acc0 = {b0,b0,b0,b0}, acc1 = {b1,b1,b1,b1};
    f32x4 acc2 = {b2,b2,b2,b2}, acc3 = {b3,b3,b3,b3};
    #pragma unroll
    for (int kc = 0; kc < 6; kc++){
      const __half* s = (kc < 2) ? A : (kc < 4) ? B : C;
      half8 a = *(const half8*)(s + (rb + col)*64 + (kc & 1)*32 + grp*8);
      acc0 = __builtin_amdgcn_mfma_f32_16x16x32_f16(a, bf[kc*4+0], acc0, 0,0,0);
      acc1 = __builtin_amdgcn_mfma_f32_16x16x32_f16(a, bf[kc*4+1], acc1, 0,0,0);
      acc2 = __builtin_amdgcn_mfma_f32_16x16x32_f16(a, bf[kc*4+2], acc2, 0,0,0);
      acc3 = __builtin_amdgcn_mfma_f32_16x16x32_f16(a, bf[kc*4+3], acc3, 0,0,0);
    }
    __half* o = out + (rb + grp*4)*64;
    #pragma unroll
    for (int r = 0; r < 4; r++){
      o[(size_t)r*64 +      col] = __float2half_rn(tanhf(acc0[r]));
      o[(size_t)r*64 + 16 + col] = __float2half_rn(tanhf(acc1[r]));
      o[(size_t)r*64 + 32 + col] = __float2half_rn(tanhf(acc2[r]));
      o[(size_t)r*64 + 48 + col] = __float2half_rn(tanhf(acc3[r]));
    }
  }
}

// ---------------- segment sums of 3 f16 buffers ----------------
__global__ void k_pool3(const __half2* __restrict__ hA, const __half2* __restrict__ hB,
                        const __half2* __restrict__ hC, float* __restrict__ pA,
                        float* __restrict__ pB, float* __restrict__ pC){
  const __half2* src = (blockIdx.y == 0) ? hA : (blockIdx.y == 1) ? hB : hC;
  float* dst         = (blockIdx.y == 0) ? pA : (blockIdx.y == 1) ? pB : pC;
  int blk = blockIdx.x;                 // 512: seg*16 + chunk
  int chunk = blk & 15, seg = blk >> 4;
  int t = threadIdx.x, ch2 = t & 31, rsub = t >> 5;
  int base = seg*8192 + chunk*512;
  float ax = 0.f, ay = 0.f;
  for (int j = 0; j < 64; j++){
    int row = base + rsub + j*8;
    float2 v = __half22float2(src[(size_t)row*32 + ch2]);
    ax += v.x; ay += v.y;
  }
  __shared__ float sx[256], sy[256];
  sx[t] = ax; sy[t] = ay; __syncthreads();
  if (t < 32){
    float tx = 0.f, ty = 0.f;
    #pragma unroll
    for (int j = 0; j < 8; j++){ tx += sx[ch2 + j*32]; ty += sy[ch2 + j*32]; }
    int b = seg >> 1, half_ = seg & 1;
    atomicAdd(&dst[half_*1024 + b*64 + ch2*2],     tx);
    atomicAdd(&dst[half_*1024 + b*64 + ch2*2 + 1], ty);
  }
}

// ---------------- pooled layer-3 combine ----------------
__global__ void k_combine_pooled(const float* __restrict__ pA, const float* __restrict__ pB,
                                 const float* __restrict__ pC, const float* __restrict__ weff,
                                 const float* __restrict__ bias, float* __restrict__ xbbsc,
                                 float* __restrict__ dout){
  int i = blockIdx.x*blockDim.x + threadIdx.x;   // 2048
  int pr = i >> 6, c = i & 63;
  const float* a = pA + pr*64;
  const float* b = pB + pr*64;
  const float* cc = pC + pr*64;
  float v = 0.f;
  for (int k = 0; k < 64; k++){
    v = fmaf(a[k],  weff[        k*64 + c], v);
    v = fmaf(b[k],  weff[4096 +  k*64 + c], v);
    v = fmaf(cc[k], weff[8192 +  k*64 + c], v);
  }
  v = v*(1.0f/8192.0f) + bias[c];
  xbbsc[i] = v;
  dout[OUT_RES + i] = v;
}

// ---------------- Cheb combine 64-ch, f32 (ref stack) ----------------
__global__ void __launch_bounds__(256) k_combine64f(
    const float* __restrict__ A, const float* __restrict__ Bm, const float* __restrict__ C,
    const float* __restrict__ Weff, const float* __restrict__ bias,
    float* __restrict__ out, int n){
  int t = threadIdx.x;
  int lane = t & 63;
  int wid  = __builtin_amdgcn_readfirstlane(t >> 6);
  int half_ = wid & 1;
  int row  = blockIdx.x*128 + (wid >> 1)*64 + lane;
  bool active = (row < n);
  float acc[32];
  #pragma unroll
  for (int c = 0; c < 32; c++) acc[c] = bias[half_*32 + c];
  if (active){
    #pragma unroll 1
    for (int m = 0; m < 3; m++){
      const float* src = (m == 0 ? A : (m == 1 ? Bm : C)) + (size_t)row*64;
      const float* Wm  = Weff + m*4096 + half_*32;
      #pragma unroll 1
      for (int k4 = 0; k4 < 16; k4++){
        float4 a4 = *(const float4*)(src + k4*4);
        const float* wk = Wm + k4*256;
        #pragma unroll
        for (int kk = 0; kk < 4; kk++){
          float a = (kk == 0) ? a4.x : (kk == 1) ? a4.y : (kk == 2) ? a4.z : a4.w;
          #pragma unroll
          for (int c = 0; c < 32; c++)
            acc[c] = fmaf(a, wk[kk*64 + c], acc[c]);
        }
      }
    }
  }
  __syncthreads();
  if (active){
    float* o = out + (size_t)row*64 + half_*32;
    #pragma unroll
    for (int c = 0; c < 32; c++) o[c] = tanhf(acc[c]);
  }
}

// ---------------- fused row-local matmul chain (ref side): 3 matmuls ----------
__global__ void k_refchain(const float* __restrict__ refA, const float* __restrict__ mlp_w,
                           const float* __restrict__ mlp2_w, const float* __restrict__ rep0_w,
                           float* __restrict__ rt3a, int n){
  int t = threadIdx.x, lane = t & 63;
  int i = blockIdx.x*4 + (t >> 6);
  if (i >= n) return;
  float v = refA[i*64 + lane];
  float a = 0.f;
  #pragma unroll
  for (int k = 0; k < 64; k++) a += __shfl(v, k, 64) * mlp_w[k*64 + lane];
  float b = 0.f;
  #pragma unroll
  for (int k = 0; k < 64; k++) b += __shfl(a, k, 64) * mlp2_w[k*64 + lane];
  float c = 0.f;
  #pragma unroll
  for (int k = 0; k < 64; k++) c += __shfl(b, k, 64) * rep0_w[k*64 + lane];
  rt3a[i*64 + lane] = c;
}

// ---------------- fused row-local chain (batch side): bb/sc terms -------------
__global__ void k_bbchain(const float* __restrict__ xbbsc,
                          const float* __restrict__ mlp_w,  const float* __restrict__ mlp_b,
                          const float* __restrict__ mlp2_w, const float* __restrict__ mlp2_b,
                          const float* __restrict__ rep0_w, const float* __restrict__ rep0_b,
                          float* __restrict__ bt3a){
  int t = threadIdx.x, lane = t & 63;
  int i = blockIdx.x*4 + (t >> 6);
  if (i >= NB) return;
  float vbb = xbbsc[i*64 + lane];
  float vsc = xbbsc[1024 + i*64 + lane];
  float a = mlp_b[lane];
  #pragma unroll
  for (int k = 0; k < 64; k++) a += __shfl(vbb, k, 64) * mlp_w[4096 + k*64 + lane];
  float b = mlp2_b[lane];
  #pragma unroll
  for (int k = 0; k < 64; k++) b += __shfl(a, k, 64) * mlp2_w[k*64 + lane];
  #pragma unroll
  for (int k = 0; k < 64; k++) b += __shfl(vsc, k, 64) * mlp2_w[4096 + k*64 + lane];
  float c = rep0_b[lane];
  #pragma unroll
  for (int k = 0; k < 64; k++) c += __shfl(b, k, 64) * rep0_w[k*64 + lane];
  bt3a[i*64 + lane] = c;
}

// ---------------- final: relu(rt3[r]+bt3[b]) -> rep1+relu -> rep2+relu ----------------
__global__ void k_final(const float* __restrict__ rt3, const float* __restrict__ bt3,
                        const float* __restrict__ W1, const float* __restrict__ b1,
                        const float* __restrict__ W2, const float* __restrict__ b2,
                        float* __restrict__ dout){
  int t = threadIdx.x, lane = t & 63;
  int g = blockIdx.x*4 + (t >> 6);
  if (g >= BRR) return;
  int b = g / RR, r = g - b*RR;
  float m = rt3[r*64 + lane] + bt3[b*64 + lane];
  m = fmaxf(m, 0.0f);
  float acc = b1[lane];
  #pragma unroll
  for (int k = 0; k < 64; k++) acc += __shfl(m, k, 64) * W1[k*64 + lane];
  float u = fmaxf(acc, 0.0f);
  float p0 = u*W2[lane*3+0], p1 = u*W2[lane*3+1], p2 = u*W2[lane*3+2];
  #pragma unroll
  for (int off = 32; off > 0; off >>= 1){
    p0 += __shfl_xor(p0, off, 64);
    p1 += __shfl_xor(p1, off, 64);
    p2 += __shfl_xor(p2, off, 64);
  }
  if (lane == 0){
    dout[g*3+0] = fmaxf(p0 + b2[0], 0.0f);
    dout[g*3+1] = fmaxf(p1 + b2[1], 0.0f);
    dout[g*3+2] = fmaxf(p2 + b2[2], 0.0f);
  }
}

extern "C" void kernel_launch(void* const* d_in, const int* in_sizes, int n_in,
                              void* d_out, int out_size, void* d_ws, size_t ws_size,
                              hipStream_t stream){
  const float* x     = (const float*)d_in[0];
  const int*   eidx  = (const int*)d_in[1];   // [2,E] flat: rows then cols
  const float* x_ref = (const float*)d_in[4];
  const int*   eref  = (const int*)d_in[5];   // [2,ER]
  const float* cw0 = (const float*)d_in[6],  *cb0 = (const float*)d_in[7];
  const float* cw1 = (const float*)d_in[8],  *cb1 = (const float*)d_in[9];
  const float* cw2 = (const float*)d_in[10], *cb2 = (const float*)d_in[11];
  const float* rw0 = (const float*)d_in[12], *rb0 = (const float*)d_in[13];
  const float* rw1 = (const float*)d_in[14], *rb1 = (const float*)d_in[15];
  const float* rw2 = (const float*)d_in[16], *rb2 = (const float*)d_in[17];
  const float* mlp_w  = (const float*)d_in[18], *mlp_b  = (const float*)d_in[19];
  const float* mlp2_w = (const float*)d_in[20], *mlp2_b = (const float*)d_in[21];
  const float* rep0_w = (const float*)d_in[22], *rep0_b = (const float*)d_in[23];
  const float* rep1_w = (const float*)d_in[24], *rep1_b = (const float*)d_in[25];
  const float* rep2_w = (const float*)d_in[26], *rep2_b = (const float*)d_in[27];
  float* out = (float*)d_out;

  // ---- workspace allocator (256B aligned) ----
  char* w = (char*)d_ws;
  size_t off = 0;
  auto alloc = [&](size_t bytes)->void*{
    void* p = w + off;
    off = (off + bytes + 255) & ~(size_t)255;
    return p;
  };
  // zero zone (single memset): deg, degR, pooled sums
  int*   deg     = (int*)  alloc(NN*4);
  int*   degR    = (int*)  alloc(RR*4);
  float* poolA   = (float*)alloc(2048*4);
  float* poolB   = (float*)alloc(2048*4);
  float* poolC   = (float*)alloc(2048*4);
  size_t zero_bytes = off;

  int*   rowptr   = (int*)  alloc((NN+1)*4);
  int*   partials = (int*)  alloc(1024*4);
  int*   rowptrR  = (int*)  alloc((RR+1)*4);
  float* dinv     = (float*)alloc(NN*4);
  float* dinvR    = (float*)alloc(RR*4);
  unsigned char* rankM = (unsigned char*)alloc(NE);
  unsigned char* rankR = (unsigned char*)alloc(ER);
  int2*  cpair    = (int2*) alloc((size_t)NE*8);
  int2*  cpairR   = (int2*) alloc((size_t)ER*8);
  float4* x4      = (float4*)alloc((size_t)NN*16);
  float4* t1_4    = (float4*)alloc((size_t)NN*16);
  float4* t2_4    = (float4*)alloc((size_t)NN*16);
  float4* xr4     = (float4*)alloc((size_t)RR*16);
  float4* rt1_4   = (float4*)alloc((size_t)RR*16);
  float4* rt2_4   = (float4*)alloc((size_t)RR*16);
  __half* hA      = (__half*)alloc((size_t)NN*64*2);
  __half* hB      = (__half*)alloc((size_t)NN*64*2);
  __half* hC      = (__half*)alloc((size_t)NN*64*2);
  float* refA     = (float*)alloc(RR*64*4);
  float* refB     = (float*)alloc(RR*64*4);
  float* refC     = (float*)alloc(RR*64*4);
  float* xbbsc    = (float*)alloc(2048*4);     // [0..1023]=x_bb, [1024..2047]=x_sc
  float* rt3a     = (float*)alloc(RR*64*4);
  float* bt3a     = (float*)alloc(NB*64*4);
  float* weffC2   = (float*)alloc(12288*4);
  float* weffR1   = (float*)alloc(12288*4);
  float* weffR2   = (float*)alloc(12288*4);
  _Float16* wfragC1 = (_Float16*)alloc(12288*2);
  (void)ws_size; (void)in_sizes; (void)n_in; (void)out_size;

  hipMemsetAsync(d_ws, 0, zero_bytes, stream);

  // ---- prep (weff x3, wpack, pads) ----
  k_prep<<<dim3(1024, 6), 256, 0, stream>>>(cw1, cw2, rw1, rw2,
                                            weffC2, weffR1, weffR2, wfragC1,
                                            x, x4, x_ref, xr4);

  // ---- CSR build: hist(+rank), scans, rank-addressed scatter (no atomics) ----
  k_hist2<<<2112, 256, 0, stream>>>(eidx, deg, rankM, eref, degR, rankR);
  k_scan1<<<1024, 256, 0, stream>>>(deg, rowptr, partials, dinv);
  k_scan2m<<<2, 1024, 0, stream>>>(partials, degR, rowptrR, dinvR);
  k_scan3<<<1024, 256, 0, stream>>>(rowptr, partials);
  k_scatter2<<<2112, 256, 0, stream>>>(eidx, dinv, rowptr, rankM, cpair,
                                       eref, dinvR, rowptrR, rankR, cpairR);

  // ---- main stack layer 1 (3-ch padded f32, f16 out) ----
  k_prop3p<<<1024, 256, 0, stream>>>(x4, t1_4, rowptr, cpair, NN);
  k_prop3p<<<1024, 256, 0, stream>>>(t1_4, t2_4, rowptr, cpair, NN);
  k_combine3h<<<NN/4, 256, 0, stream>>>(x4, t1_4, t2_4, cw0, cb0, hA, NN);
  // ---- layer 2 (f16 features, MFMA combine) ----
  k_prop64h<<<NN/32, 256, 0, stream>>>((const uint4*)hA, (uint4*)hB, rowptr, cpair, NN);
  k_prop64h<<<NN/32, 256, 0, stream>>>((const uint4*)hB, (uint4*)hC, rowptr, cpair, NN);
  k_combine64m<<<1024, 256, 0, stream>>>(hA, hB, hC, wfragC1, cb1, hA, NN/16, 4096);
  // ---- layer 3: props, then pooled (linear) combine ----
  k_prop64h<<<NN/32, 256, 0, stream>>>((const uint4*)hA, (uint4*)hB, rowptr, cpair, NN);
  k_prop64h<<<NN/32, 256, 0, stream>>>((const uint4*)hB, (uint4*)hC, rowptr, cpair, NN);
  k_pool3<<<dim3(512,3), 256, 0, stream>>>((const __half2*)hA, (const __half2*)hB,
                                           (const __half2*)hC, poolA, poolB, poolC);
  k_combine_pooled<<<8, 256, 0, stream>>>(poolA, poolB, poolC, weffC2, cb2, xbbsc, out);

  // ---- reference stack (f32; tanh after every layer incl. last — source bug) ----
  k_prop3p<<<9, 256, 0, stream>>>(xr4, rt1_4, rowptrR, cpairR, RR);
  k_prop3p<<<9, 256, 0, stream>>>(rt1_4, rt2_4, rowptrR, cpairR, RR);
  k_combine3f<<<548, 256, 0, stream>>>(xr4, rt1_4, rt2_4, rw0, rb0, refA, RR);
  k_prop64<<<548, 256, 0, stream>>>(refA, refB, rowptrR, cpairR, RR);
  k_prop64<<<548, 256, 0, stream>>>(refB, refC, rowptrR, cpairR, RR);
  k_combine64f<<<(RR+127)/128, 256, 0, stream>>>(refA, refB, refC, weffR1, rb1, refA, RR);
  k_prop64<<<548, 256, 0, stream>>>(refA, refB, rowptrR, cpairR, RR);
  k_prop64<<<548, 256, 0, stream>>>(refB, refC, rowptrR, cpairR, RR);
  k_combine64f<<<(RR+127)/128, 256, 0, stream>>>(refA, refB, refC, weffR2, rb2, refA, RR);

  // ---- collapsed MLP head (fused row-local chains) ----
  k_refchain<<<548, 256, 0, stream>>>(refA, mlp_w, mlp2_w, rep0_w, rt3a, RR);
  k_bbchain<<<4, 256, 0, stream>>>(xbbsc, mlp_w, mlp_b, mlp2_w, mlp2_b, rep0_w, rep0_b, bt3a);

  k_final<<<(BRR+3)/4, 256, 0, stream>>>(rt3a, bt3a, rep1_w, rep1_b, rep2_w, rep2_b, out);
}

// Round 10
// 673.121 us; speedup vs baseline: 1.2925x; 1.0758x over previous
//
#include <hip/hip_runtime.h>
#include <hip/hip_fp16.h>
#include <math.h>

#define NN 262144        // total nodes
#define NE 2097152       // total edges
#define RR 2191          // ref nodes
#define ER (RR*16)       // ref edges = 35056
#define NB 16            // batch graphs
#define BRR (NB*RR)      // 35056
#define OUT_RES (BRR*3)  // 105168

typedef __attribute__((ext_vector_type(8))) _Float16 half8;
typedef __attribute__((ext_vector_type(4))) float f32x4;

// ================= merged histogram + prep =================
// blocks: [0,2048) main hist | [2048,2112) ref hist | [2112,2160) weff x3
//         [2160,2208) wpack | [2208,3232) pad x | [3232,3241) pad x_ref
__global__ void k_histprep(const int* __restrict__ eM, int* __restrict__ degM,
                           unsigned char* __restrict__ rankM,
                           const int* __restrict__ eR, int* __restrict__ degR,
                           unsigned char* __restrict__ rankR,
                           const float* __restrict__ cw1, const float* __restrict__ cw2,
                           const float* __restrict__ rw1, const float* __restrict__ rw2,
                           float* __restrict__ weffC2, float* __restrict__ weffR1,
                           float* __restrict__ weffR2, _Float16* __restrict__ wfragC1,
                           const float* __restrict__ x, float4* __restrict__ x4,
                           const float* __restrict__ x_ref, float4* __restrict__ xr4){
  int b = blockIdx.x, t = threadIdx.x;
  if (b < 2048){
    for (int i = b*256 + t; i < NE; i += 2048*256){
      int old = atomicAdd(&degM[eM[i]], 1);
      rankM[i] = (unsigned char)old;
    }
  } else if (b < 2112){
    for (int i = (b-2048)*256 + t; i < ER; i += 64*256){
      int old = atomicAdd(&degR[eR[i]], 1);
      rankR[i] = (unsigned char)old;
    }
  } else if (b < 2160){
    int y = (b - 2112) >> 4;             // 0..2
    int i = ((b - 2112) & 15)*256 + t;   // 0..4095
    const float* W = (y == 0) ? cw2 : (y == 1) ? rw1 : rw2;
    float* D       = (y == 0) ? weffC2 : (y == 1) ? weffR1 : weffR2;
    D[i]        = W[i] - W[8192 + i];
    D[4096 + i] = W[4096 + i];
    D[8192 + i] = 2.0f * W[8192 + i];
  } else if (b < 2208){
    int i = (b - 2160)*256 + t;          // 0..12287
    int reg = i & 7, lane = (i >> 3) & 63, nt = (i >> 9) & 3, kc = i >> 11;
    int m = kc >> 1;
    int kin = (kc & 1)*32 + ((lane >> 4) & 3)*8 + reg;
    int n = nt*16 + (lane & 15);
    float eff;
    if      (m == 0) eff = cw1[kin*64 + n] - cw1[8192 + kin*64 + n];
    else if (m == 1) eff = cw1[4096 + kin*64 + n];
    else             eff = 2.0f * cw1[8192 + kin*64 + n];
    wfragC1[i] = (_Float16)eff;
  } else if (b < 3232){
    int i = (b - 2208)*256 + t;
    if (i < NN) x4[i] = make_float4(x[i*3], x[i*3+1], x[i*3+2], 0.0f);
  } else {
    int i = (b - 3232)*256 + t;
    if (i < RR) xr4[i] = make_float4(x_ref[i*3], x_ref[i*3+1], x_ref[i*3+2], 0.0f);
  }
}

// ================= scans =================
__global__ void k_scan1(const int* __restrict__ deg, int* __restrict__ rowptr,
                        int* __restrict__ partials, float* __restrict__ dinv){
  __shared__ int s[256];
  int t = threadIdx.x; int i = blockIdx.x*256 + t;
  int v = deg[i]; s[t] = v; __syncthreads();
  dinv[i] = v > 0 ? 1.0f/sqrtf((float)v) : 0.0f;
  for (int off = 1; off < 256; off <<= 1){
    int x = (t >= off) ? s[t-off] : 0; __syncthreads();
    s[t] += x; __syncthreads();
  }
  rowptr[i] = s[t] - v;
  if (t == 255) partials[blockIdx.x] = s[255];
}

__global__ void __launch_bounds__(1024) k_scan2m(int* __restrict__ partials,
                                                 const int* __restrict__ degR,
                                                 int* __restrict__ rowptrR,
                                                 float* __restrict__ dinvR){
  __shared__ int s[1024];
  int t = threadIdx.x;
  if (blockIdx.x == 0){
    int v = partials[t]; s[t] = v; __syncthreads();
    for (int off = 1; off < 1024; off <<= 1){
      int x = (t >= off) ? s[t-off] : 0; __syncthreads();
      s[t] += x; __syncthreads();
    }
    partials[t] = s[t] - v;
  } else {
    int carry = 0;
    for (int base = 0; base < RR; base += 1024){
      int idx = base + t;
      int v = (idx < RR) ? degR[idx] : 0;
      if (idx < RR) dinvR[idx] = v > 0 ? 1.0f/sqrtf((float)v) : 0.0f;
      s[t] = v; __syncthreads();
      for (int off = 1; off < 1024; off <<= 1){
        int x = (t >= off) ? s[t-off] : 0; __syncthreads();
        s[t] += x; __syncthreads();
      }
      if (idx < RR) rowptrR[idx] = carry + s[t] - v;
      carry += s[1023];
      __syncthreads();
    }
    if (t == 0) rowptrR[RR] = carry;
  }
}

__global__ void k_scan3(int* __restrict__ rowptr, const int* __restrict__ partials){
  int t = threadIdx.x; int i = blockIdx.x*256 + t;
  rowptr[i] += partials[blockIdx.x];
  if (i == 0) rowptr[NN] = NE;
}

// ================= merged scatter (rank-addressed, no atomics) =================
__global__ void k_scatter2(const int* __restrict__ eM, const float* __restrict__ dinv,
                           const int* __restrict__ rowptr, const unsigned char* __restrict__ rankM,
                           int2* __restrict__ pair,
                           const int* __restrict__ eR, const float* __restrict__ dinvR,
                           const int* __restrict__ rowptrR, const unsigned char* __restrict__ rankR,
                           int2* __restrict__ pairR){
  int b = blockIdx.x;
  if (b < 2048){
    for (int i = b*256 + threadIdx.x; i < NE; i += 2048*256){
      int r = eM[i], c = eM[NE + i];
      int pos = rowptr[r] + rankM[i];
      unsigned wbits = (unsigned)__float_as_int(-dinv[r]*dinv[c]);
      long long v = (unsigned)c | ((long long)wbits << 32);
      __builtin_nontemporal_store(v, (long long*)(pair + pos));
    }
  } else {
    for (int i = (b-2048)*256 + threadIdx.x; i < ER; i += 64*256){
      int r = eR[i], c = eR[ER + i];
      int pos = rowptrR[r] + rankR[i];
      unsigned wbits = (unsigned)__float_as_int(-dinvR[r]*dinvR[c]);
      long long v = (unsigned)c | ((long long)wbits << 32);
      __builtin_nontemporal_store(v, (long long*)(pairR + pos));
    }
  }
}

// ================= device bodies =================
__device__ __forceinline__ void prop3_body(const float4* __restrict__ h, float4* __restrict__ y,
                                           const int* __restrict__ rowptr,
                                           const int2* __restrict__ pair, int i){
  float a0 = 0.f, a1 = 0.f, a2 = 0.f;
  int s = rowptr[i], e = rowptr[i+1];
  int p = s;
  for (; p + 4 <= e; p += 4){
    int2 q0 = pair[p], q1 = pair[p+1], q2 = pair[p+2], q3 = pair[p+3];
    float4 v0 = h[q0.x], v1 = h[q1.x], v2 = h[q2.x], v3 = h[q3.x];
    float w0 = __int_as_float(q0.y), w1 = __int_as_float(q1.y);
    float w2 = __int_as_float(q2.y), w3 = __int_as_float(q3.y);
    a0 = fmaf(w0,v0.x, fmaf(w1,v1.x, fmaf(w2,v2.x, fmaf(w3,v3.x, a0))));
    a1 = fmaf(w0,v0.y, fmaf(w1,v1.y, fmaf(w2,v2.y, fmaf(w3,v3.y, a1))));
    a2 = fmaf(w0,v0.z, fmaf(w1,v1.z, fmaf(w2,v2.z, fmaf(w3,v3.z, a2))));
  }
  for (; p < e; p++){
    int2 q = pair[p]; float wv = __int_as_float(q.y);
    float4 v = h[q.x];
    a0 = fmaf(wv, v.x, a0); a1 = fmaf(wv, v.y, a1); a2 = fmaf(wv, v.z, a2);
  }
  y[i] = make_float4(a0, a1, a2, 0.0f);
}

__device__ __forceinline__ void combine3_body(const float4* __restrict__ x,
                                              const float4* __restrict__ t1,
                                              const float4* __restrict__ t2,
                                              const float* __restrict__ W,
                                              const float* __restrict__ bias,
                                              int i, int lane, float* accout){
  float4 px = x[i], p1 = t1[i], p2 = t2[i];
  const float* fx = (const float*)&px;
  const float* f1 = (const float*)&p1;
  const float* f2 = (const float*)&p2;
  float acc = bias[lane];
  #pragma unroll
  for (int j = 0; j < 3; j++){
    float x0 = fx[j], x1 = f1[j];
    float x2 = 2.0f*f2[j] - x0;
    acc += x0*W[      j*64 + lane]
         + x1*W[192 + j*64 + lane]
         + x2*W[384 + j*64 + lane];
  }
  *accout = tanhf(acc);
}

__device__ __forceinline__ void prop64f_body(const float* __restrict__ h, float* __restrict__ y,
                                             const int* __restrict__ rowptr,
                                             const int2* __restrict__ pair, int i, int lane){
  float acc = 0.f;
  int s = rowptr[i], e = rowptr[i+1];
  int p = s;
  for (; p + 4 <= e; p += 4){
    int2 q0 = pair[p], q1 = pair[p+1], q2 = pair[p+2], q3 = pair[p+3];
    float v0 = h[(size_t)q0.x*64 + lane], v1 = h[(size_t)q1.x*64 + lane];
    float v2 = h[(size_t)q2.x*64 + lane], v3 = h[(size_t)q3.x*64 + lane];
    acc = fmaf(__int_as_float(q0.y),v0, fmaf(__int_as_float(q1.y),v1,
          fmaf(__int_as_float(q2.y),v2, fmaf(__int_as_float(q3.y),v3, acc))));
  }
  for (; p < e; p++){
    int2 q = pair[p];
    acc = fmaf(__int_as_float(q.y), h[(size_t)q.x*64 + lane], acc);
  }
  y[(size_t)i*64 + lane] = acc;
}

// ref-stack Cheb combine (f32, tanh) — callable from merged kernels
__device__ __forceinline__ void combine64f_body(const float* __restrict__ A,
                                                const float* __restrict__ Bm,
                                                const float* __restrict__ C,
                                                const float* __restrict__ Weff,
                                                const float* __restrict__ bias,
                                                float* __restrict__ out, int n,
                                                int blk, int t){
  int lane = t & 63;
  int wid  = __builtin_amdgcn_readfirstlane(t >> 6);
  int half_ = wid & 1;
  int row  = blk*128 + (wid >> 1)*64 + lane;
  bool active = (row < n);
  float acc[32];
  #pragma unroll
  for (int c = 0; c < 32; c++) acc[c] = bias[half_*32 + c];
  if (active){
    #pragma unroll 1
    for (int m = 0; m < 3; m++){
      const float* src = (m == 0 ? A : (m == 1 ? Bm : C)) + (size_t)row*64;
      const float* Wm  = Weff + m*4096 + half_*32;
      #pragma unroll 1
      for (int k4 = 0; k4 < 16; k4++){
        float4 a4 = *(const float4*)(src + k4*4);
        const float* wk = Wm + k4*256;
        #pragma unroll
        for (int kk = 0; kk < 4; kk++){
          float a = (kk == 0) ? a4.x : (kk == 1) ? a4.y : (kk == 2) ? a4.z : a4.w;
          #pragma unroll
          for (int c = 0; c < 32; c++)
            acc[c] = fmaf(a, wk[kk*64 + c], acc[c]);
        }
      }
    }
  }
  __syncthreads();
  if (active){
    float* o = out + (size_t)row*64 + half_*32;
    #pragma unroll
    for (int c = 0; c < 32; c++) o[c] = tanhf(acc[c]);
  }
}

// ================= merged prop3 (main + ref) =================
__global__ void k_prop3m(const float4* __restrict__ hM, float4* __restrict__ yM,
                         const int* __restrict__ rowptr, const int2* __restrict__ pair,
                         const float4* __restrict__ hR, float4* __restrict__ yR,
                         const int* __restrict__ rowptrR, const int2* __restrict__ pairR){
  int b = blockIdx.x, t = threadIdx.x;
  if (b < 1024){
    prop3_body(hM, yM, rowptr, pair, b*256 + t);
  } else {
    int i = (b - 1024)*256 + t;
    if (i < RR) prop3_body(hR, yR, rowptrR, pairR, i);
  }
}

// ================= merged combine3 (main f16 + ref f32) =================
__global__ void k_combine3m(const float4* __restrict__ x, const float4* __restrict__ t1,
                            const float4* __restrict__ t2, const float* __restrict__ cW,
                            const float* __restrict__ cb, __half* __restrict__ outM,
                            const float4* __restrict__ xr, const float4* __restrict__ r1,
                            const float4* __restrict__ r2, const float* __restrict__ rW,
                            const float* __restrict__ rb, float* __restrict__ outR){
  int b = blockIdx.x, t = threadIdx.x, lane = t & 63;
  if (b < 65536){
    int i = b*4 + (t >> 6);
    float v; combine3_body(x, t1, t2, cW, cb, i, lane, &v);
    outM[(size_t)i*64 + lane] = __float2half_rn(v);
  } else {
    int i = (b - 65536)*4 + (t >> 6);
    if (i < RR){
      float v; combine3_body(xr, r1, r2, rW, rb, i, lane, &v);
      outR[(size_t)i*64 + lane] = v;
    }
  }
}

// ================= merged prop64 (main f16 + ref f32) =================
__global__ void __launch_bounds__(256) k_prop64m(
    const uint4* __restrict__ h4, uint4* __restrict__ y4,
    const int* __restrict__ rowptr, const int2* __restrict__ pair,
    const float* __restrict__ hR, float* __restrict__ yR,
    const int* __restrict__ rowptrR, const int2* __restrict__ pairR){
  int b = blockIdx.x, t = threadIdx.x;
  if (b >= 8192){
    int i = (b - 8192)*4 + (t >> 6);
    if (i < RR) prop64f_body(hR, yR, rowptrR, pairR, i, t & 63);
    return;
  }
  int sub = t & 7;                      // 16B chunk within the 128B row
  int row = b*32 + (t >> 3);
  int s = rowptr[row], e = rowptr[row+1];
  float ac[8];
  #pragma unroll
  for (int k = 0; k < 8; k++) ac[k] = 0.f;
  int p = s;
  for (; p + 8 <= e; p += 8){
    int2 q[8]; uint4 v[8];
    #pragma unroll
    for (int j = 0; j < 8; j++) q[j] = pair[p+j];
    #pragma unroll
    for (int j = 0; j < 8; j++) v[j] = h4[(size_t)q[j].x*8 + sub];
    #pragma unroll
    for (int j = 0; j < 8; j++){
      float wv = __int_as_float(q[j].y);
      #pragma unroll
      for (int k = 0; k < 4; k++){
        float2 f = __half22float2(((const __half2*)&v[j])[k]);
        ac[2*k]   = fmaf(wv, f.x, ac[2*k]);
        ac[2*k+1] = fmaf(wv, f.y, ac[2*k+1]);
      }
    }
  }
  for (; p + 4 <= e; p += 4){
    int2 q[4]; uint4 v[4];
    #pragma unroll
    for (int j = 0; j < 4; j++) q[j] = pair[p+j];
    #pragma unroll
    for (int j = 0; j < 4; j++) v[j] = h4[(size_t)q[j].x*8 + sub];
    #pragma unroll
    for (int j = 0; j < 4; j++){
      float wv = __int_as_float(q[j].y);
      #pragma unroll
      for (int k = 0; k < 4; k++){
        float2 f = __half22float2(((const __half2*)&v[j])[k]);
        ac[2*k]   = fmaf(wv, f.x, ac[2*k]);
        ac[2*k+1] = fmaf(wv, f.y, ac[2*k+1]);
      }
    }
  }
  for (; p < e; p++){
    int2 q = pair[p];
    float wv = __int_as_float(q.y);
    uint4 v = h4[(size_t)q.x*8 + sub];
    #pragma unroll
    for (int k = 0; k < 4; k++){
      float2 f = __half22float2(((const __half2*)&v)[k]);
      ac[2*k]   = fmaf(wv, f.x, ac[2*k]);
      ac[2*k+1] = fmaf(wv, f.y, ac[2*k+1]);
    }
  }
  uint4 r;
  #pragma unroll
  for (int k = 0; k < 4; k++){
    __half2 hp = __floats2half2_rn(ac[2*k], ac[2*k+1]);
    ((unsigned*)&r)[k] = *(unsigned*)&hp;
  }
  y4[(size_t)row*8 + sub] = r;
}

// ================= merged: main MFMA combine + ref combine64f =================
__global__ void __launch_bounds__(256) k_combine64mm(
    const __half* A, const __half* B, const __half* C,
    const _Float16* __restrict__ wfrag, const float* __restrict__ bias,
    __half* out, int ntiles, int wavestride,
    const float* __restrict__ rA, const float* __restrict__ rB, const float* __restrict__ rC,
    const float* __restrict__ weffR, const float* __restrict__ biasR,
    float* __restrict__ outR){
  int t = threadIdx.x;
  if (blockIdx.x >= 1024){
    combine64f_body(rA, rB, rC, weffR, biasR, outR, RR, blockIdx.x - 1024, t);
    return;
  }
  int lane = t & 63;
  int wv = blockIdx.x*4 + (t >> 6);
  half8 bf[24];
  #pragma unroll
  for (int i = 0; i < 24; i++)
    bf[i] = *(const half8*)(wfrag + ((size_t)(i*64 + lane))*8);
  int col = lane & 15, grp = (lane >> 4) & 3;
  float b0 = bias[col], b1 = bias[16+col], b2 = bias[32+col], b3 = bias[48+col];
  for (int tile = wv; tile < ntiles; tile += wavestride){
    size_t rb = (size_t)tile*16;
    f32x4 acc0 = {b0,b0,b0,b0}, acc1 = {b1,b1,b1,b1};
    f32x4 acc2 = {b2,b2,b2,b2}, acc3 = {b3,b3,b3,b3};
    #pragma unroll
    for (int kc = 0; kc < 6; kc++){
      const __half* s = (kc < 2) ? A : (kc < 4) ? B : C;
      half8 a = *(const half8*)(s + (rb + col)*64 + (kc & 1)*32 + grp*8);
      acc0 = __builtin_amdgcn_mfma_f32_16x16x32_f16(a, bf[kc*4+0], acc0, 0,0,0);
      acc1 = __builtin_amdgcn_mfma_f32_16x16x32_f16(a, bf[kc*4+1], acc1, 0,0,0);
      acc2 = __builtin_amdgcn_mfma_f32_16x16x32_f16(a, bf[kc*4+2], acc2, 0,0,0);
      acc3 = __builtin_amdgcn_mfma_f32_16x16x32_f16(a, bf[kc*4+3], acc3, 0,0,0);
    }
    __half* o = out + (rb + grp*4)*64;
    #pragma unroll
    for (int r = 0; r < 4; r++){
      o[(size_t)r*64 +      col] = __float2half_rn(tanhf(acc0[r]));
      o[(size_t)r*64 + 16 + col] = __float2half_rn(tanhf(acc1[r]));
      o[(size_t)r*64 + 32 + col] = __float2half_rn(tanhf(acc2[r]));
      o[(size_t)r*64 + 48 + col] = __float2half_rn(tanhf(acc3[r]));
    }
  }
}

// ================= merged: main pool3 + ref final combine64f =================
__global__ void k_tail3(const __half2* __restrict__ hA, const __half2* __restrict__ hB,
                        const __half2* __restrict__ hC, float* __restrict__ pA,
                        float* __restrict__ pB, float* __restrict__ pC,
                        const float* __restrict__ rA, const float* __restrict__ rB,
                        const float* __restrict__ rC, const float* __restrict__ weffR,
                        const float* __restrict__ biasR, float* __restrict__ outR){
  int b = blockIdx.x, t = threadIdx.x;
  if (b >= 1536){
    combine64f_body(rA, rB, rC, weffR, biasR, outR, RR, b - 1536, t);
    return;
  }
  int y = b >> 9;                        // 0..2 (512 blocks each)
  const __half2* src = (y == 0) ? hA : (y == 1) ? hB : hC;
  float* dst         = (y == 0) ? pA : (y == 1) ? pB : pC;
  int blk = b & 511;
  int chunk = blk & 15, seg = blk >> 4;
  int ch2 = t & 31, rsub = t >> 5;
  int base = seg*8192 + chunk*512;
  float ax = 0.f, ay = 0.f;
  for (int j = 0; j < 64; j++){
    int row = base + rsub + j*8;
    float2 v = __half22float2(src[(size_t)row*32 + ch2]);
    ax += v.x; ay += v.y;
  }
  __shared__ float sx[256], sy[256];
  sx[t] = ax; sy[t] = ay; __syncthreads();
  if (t < 32){
    float tx = 0.f, ty = 0.f;
    #pragma unroll
    for (int j = 0; j < 8; j++){ tx += sx[ch2 + j*32]; ty += sy[ch2 + j*32]; }
    int bb = seg >> 1, half_ = seg & 1;
    atomicAdd(&dst[half_*1024 + bb*64 + ch2*2],     tx);
    atomicAdd(&dst[half_*1024 + bb*64 + ch2*2 + 1], ty);
  }
}

// ================= merged: pooled combine + refchain =================
__global__ void k_cpr(const float* __restrict__ pA, const float* __restrict__ pB,
                      const float* __restrict__ pC, const float* __restrict__ weff,
                      const float* __restrict__ bias, float* __restrict__ xbbsc,
                      float* __restrict__ dout,
                      const float* __restrict__ refA, const float* __restrict__ mlp_w,
                      const float* __restrict__ mlp2_w, const float* __restrict__ rep0_w,
                      float* __restrict__ rt3a){
  int b = blockIdx.x, t = threadIdx.x;
  if (b < 8){
    int i = b*256 + t;
    int pr = i >> 6, c = i & 63;
    const float* a = pA + pr*64;
    const float* bb = pB + pr*64;
    const float* cc = pC + pr*64;
    float v = 0.f;
    for (int k = 0; k < 64; k++){
      v = fmaf(a[k],  weff[        k*64 + c], v);
      v = fmaf(bb[k], weff[4096 +  k*64 + c], v);
      v = fmaf(cc[k], weff[8192 +  k*64 + c], v);
    }
    v = v*(1.0f/8192.0f) + bias[c];
    xbbsc[i] = v;
    dout[OUT_RES + i] = v;
  } else {
    int lane = t & 63;
    int i = (b - 8)*4 + (t >> 6);
    if (i >= RR) return;
    float v = refA[i*64 + lane];
    float a = 0.f;
    #pragma unroll
    for (int k = 0; k < 64; k++) a += __shfl(v, k, 64) * mlp_w[k*64 + lane];
    float bb = 0.f;
    #pragma unroll
    for (int k = 0; k < 64; k++) bb += __shfl(a, k, 64) * mlp2_w[k*64 + lane];
    float c = 0.f;
    #pragma unroll
    for (int k = 0; k < 64; k++) c += __shfl(bb, k, 64) * rep0_w[k*64 + lane];
    rt3a[i*64 + lane] = c;
  }
}

// ================= bb/sc chain =================
__global__ void k_bbchain(const float* __restrict__ xbbsc,
                          const float* __restrict__ mlp_w,  const float* __restrict__ mlp_b,
                          const float* __restrict__ mlp2_w, const float* __restrict__ mlp2_b,
                          const float* __restrict__ rep0_w, const float* __restrict__ rep0_b,
                          float* __restrict__ bt3a){
  int t = threadIdx.x, lane = t & 63;
  int i = blockIdx.x*4 + (t >> 6);
  if (i >= NB) return;
  float vbb = xbbsc[i*64 + lane];
  float vsc = xbbsc[1024 + i*64 + lane];
  float a = mlp_b[lane];
  #pragma unroll
  for (int k = 0; k < 64; k++) a += __shfl(vbb, k, 64) * mlp_w[4096 + k*64 + lane];
  float b = mlp2_b[lane];
  #pragma unroll
  for (int k = 0; k < 64; k++) b += __shfl(a, k, 64) * mlp2_w[k*64 + lane];
  #pragma unroll
  for (int k = 0; k < 64; k++) b += __shfl(vsc, k, 64) * mlp2_w[4096 + k*64 + lane];
  float c = rep0_b[lane];
  #pragma unroll
  for (int k = 0; k < 64; k++) c += __shfl(b, k, 64) * rep0_w[k*64 + lane];
  bt3a[i*64 + lane] = c;
}

// ================= final =================
__global__ void k_final(const float* __restrict__ rt3, const float* __restrict__ bt3,
                        const float* __restrict__ W1, const float* __restrict__ b1,
                        const float* __restrict__ W2, const float* __restrict__ b2,
                        float* __restrict__ dout){
  int t = threadIdx.x, lane = t & 63;
  int g = blockIdx.x*4 + (t >> 6);
  if (g >= BRR) return;
  int b = g / RR, r = g - b*RR;
  float m = rt3[r*64 + lane] + bt3[b*64 + lane];
  m = fmaxf(m, 0.0f);
  float acc = b1[lane];
  #pragma unroll
  for (int k = 0; k < 64; k++) acc += __shfl(m, k, 64) * W1[k*64 + lane];
  float u = fmaxf(acc, 0.0f);
  float p0 = u*W2[lane*3+0], p1 = u*W2[lane*3+1], p2 = u*W2[lane*3+2];
  #pragma unroll
  for (int off = 32; off > 0; off >>= 1){
    p0 += __shfl_xor(p0, off, 64);
    p1 += __shfl_xor(p1, off, 64);
    p2 += __shfl_xor(p2, off, 64);
  }
  if (lane == 0){
    dout[g*3+0] = fmaxf(p0 + b2[0], 0.0f);
    dout[g*3+1] = fmaxf(p1 + b2[1], 0.0f);
    dout[g*3+2] = fmaxf(p2 + b2[2], 0.0f);
  }
}

extern "C" void kernel_launch(void* const* d_in, const int* in_sizes, int n_in,
                              void* d_out, int out_size, void* d_ws, size_t ws_size,
                              hipStream_t stream){
  const float* x     = (const float*)d_in[0];
  const int*   eidx  = (const int*)d_in[1];   // [2,E] flat: rows then cols
  const float* x_ref = (const float*)d_in[4];
  const int*   eref  = (const int*)d_in[5];   // [2,ER]
  const float* cw0 = (const float*)d_in[6],  *cb0 = (const float*)d_in[7];
  const float* cw1 = (const float*)d_in[8],  *cb1 = (const float*)d_in[9];
  const float* cw2 = (const float*)d_in[10], *cb2 = (const float*)d_in[11];
  const float* rw0 = (const float*)d_in[12], *rb0 = (const float*)d_in[13];
  const float* rw1 = (const float*)d_in[14], *rb1 = (const float*)d_in[15];
  const float* rw2 = (const float*)d_in[16], *rb2 = (const float*)d_in[17];
  const float* mlp_w  = (const float*)d_in[18], *mlp_b  = (const float*)d_in[19];
  const float* mlp2_w = (const float*)d_in[20], *mlp2_b = (const float*)d_in[21];
  const float* rep0_w = (const float*)d_in[22], *rep0_b = (const float*)d_in[23];
  const float* rep1_w = (const float*)d_in[24], *rep1_b = (const float*)d_in[25];
  const float* rep2_w = (const float*)d_in[26], *rep2_b = (const float*)d_in[27];
  float* out = (float*)d_out;

  // ---- workspace allocator (256B aligned) ----
  char* w = (char*)d_ws;
  size_t off = 0;
  auto alloc = [&](size_t bytes)->void*{
    void* p = w + off;
    off = (off + bytes + 255) & ~(size_t)255;
    return p;
  };
  // zero zone (single memset): deg, degR, pooled sums
  int*   deg     = (int*)  alloc(NN*4);
  int*   degR    = (int*)  alloc(RR*4);
  float* poolA   = (float*)alloc(2048*4);
  float* poolB   = (float*)alloc(2048*4);
  float* poolC   = (float*)alloc(2048*4);
  size_t zero_bytes = off;

  int*   rowptr   = (int*)  alloc((NN+1)*4);
  int*   partials = (int*)  alloc(1024*4);
  int*   rowptrR  = (int*)  alloc((RR+1)*4);
  float* dinv     = (float*)alloc(NN*4);
  float* dinvR    = (float*)alloc(RR*4);
  unsigned char* rankM = (unsigned char*)alloc(NE);
  unsigned char* rankR = (unsigned char*)alloc(ER);
  int2*  cpair    = (int2*) alloc((size_t)NE*8);
  int2*  cpairR   = (int2*) alloc((size_t)ER*8);
  float4* x4      = (float4*)alloc((size_t)NN*16);
  float4* t1_4    = (float4*)alloc((size_t)NN*16);
  float4* t2_4    = (float4*)alloc((size_t)NN*16);
  float4* xr4     = (float4*)alloc((size_t)RR*16);
  float4* rt1_4   = (float4*)alloc((size_t)RR*16);
  float4* rt2_4   = (float4*)alloc((size_t)RR*16);
  __half* hA      = (__half*)alloc((size_t)NN*64*2);
  __half* hB      = (__half*)alloc((size_t)NN*64*2);
  __half* hC      = (__half*)alloc((size_t)NN*64*2);
  float* refA     = (float*)alloc(RR*64*4);
  float* refB     = (float*)alloc(RR*64*4);
  float* refC     = (float*)alloc(RR*64*4);
  float* xbbsc    = (float*)alloc(2048*4);     // [0..1023]=x_bb, [1024..2047]=x_sc
  float* rt3a     = (float*)alloc(RR*64*4);
  float* bt3a     = (float*)alloc(NB*64*4);
  float* weffC2   = (float*)alloc(12288*4);
  float* weffR1   = (float*)alloc(12288*4);
  float* weffR2   = (float*)alloc(12288*4);
  _Float16* wfragC1 = (_Float16*)alloc(12288*2);
  (void)ws_size; (void)in_sizes; (void)n_in; (void)out_size;

  hipMemsetAsync(d_ws, 0, zero_bytes, stream);

  // ---- hist (+rank) merged with prep ----
  k_histprep<<<3241, 256, 0, stream>>>(eidx, deg, rankM, eref, degR, rankR,
                                       cw1, cw2, rw1, rw2,
                                       weffC2, weffR1, weffR2, wfragC1,
                                       x, x4, x_ref, xr4);
  k_scan1<<<1024, 256, 0, stream>>>(deg, rowptr, partials, dinv);
  k_scan2m<<<2, 1024, 0, stream>>>(partials, degR, rowptrR, dinvR);
  k_scan3<<<1024, 256, 0, stream>>>(rowptr, partials);
  k_scatter2<<<2112, 256, 0, stream>>>(eidx, dinv, rowptr, rankM, cpair,
                                       eref, dinvR, rowptrR, rankR, cpairR);

  // ---- layer 1 (main + ref merged) ----
  k_prop3m<<<1033, 256, 0, stream>>>(x4, t1_4, rowptr, cpair, xr4, rt1_4, rowptrR, cpairR);
  k_prop3m<<<1033, 256, 0, stream>>>(t1_4, t2_4, rowptr, cpair, rt1_4, rt2_4, rowptrR, cpairR);
  k_combine3m<<<66084, 256, 0, stream>>>(x4, t1_4, t2_4, cw0, cb0, hA,
                                         xr4, rt1_4, rt2_4, rw0, rb0, refA);
  // ---- layer 2 ----
  k_prop64m<<<8740, 256, 0, stream>>>((const uint4*)hA, (uint4*)hB, rowptr, cpair,
                                      refA, refB, rowptrR, cpairR);
  k_prop64m<<<8740, 256, 0, stream>>>((const uint4*)hB, (uint4*)hC, rowptr, cpair,
                                      refB, refC, rowptrR, cpairR);
  k_combine64mm<<<1042, 256, 0, stream>>>(hA, hB, hC, wfragC1, cb1, hA, NN/16, 4096,
                                          refA, refB, refC, weffR1, rb1, refA);
  // ---- layer 3 ----
  k_prop64m<<<8740, 256, 0, stream>>>((const uint4*)hA, (uint4*)hB, rowptr, cpair,
                                      refA, refB, rowptrR, cpairR);
  k_prop64m<<<8740, 256, 0, stream>>>((const uint4*)hB, (uint4*)hC, rowptr, cpair,
                                      refB, refC, rowptrR, cpairR);
  k_tail3<<<1554, 256, 0, stream>>>((const __half2*)hA, (const __half2*)hB, (const __half2*)hC,
                                    poolA, poolB, poolC,
                                    refA, refB, refC, weffR2, rb2, refA);
  // ---- head ----
  k_cpr<<<556, 256, 0, stream>>>(poolA, poolB, poolC, weffC2, cb2, xbbsc, out,
                                 refA, mlp_w, mlp2_w, rep0_w, rt3a);
  k_bbchain<<<4, 256, 0, stream>>>(xbbsc, mlp_w, mlp_b, mlp2_w, mlp2_b, rep0_w, rep0_b, bt3a);
  k_final<<<(BRR+3)/4, 256, 0, stream>>>(rt3a, bt3a, rep1_w, rep1_b, rep2_w, rep2_b, out);
}